// Round 8
// baseline (193.396 us; speedup 1.0000x reference)
//
#include <hip/hip_runtime.h>
#include <hip/hip_bf16.h>

// ---------------------------------------------------------------------------
// Transformer block: LN(h + (softmax(mask(QK^T))V)Wo + sigmoid(hW1)*(hW2))
// B=2 S=2048 D_MODEL=1024 H=16 DH=64.  All heavy math in bf16 MFMA.
// ---------------------------------------------------------------------------

typedef short bf16x8 __attribute__((ext_vector_type(8)));   // 8 bf16 = 4 VGPR
typedef float f32x4  __attribute__((ext_vector_type(4)));
typedef float f32x16 __attribute__((ext_vector_type(16)));
typedef unsigned int u32x4 __attribute__((ext_vector_type(4)));

typedef const __attribute__((address_space(1))) void* gas_cvp;
typedef __attribute__((address_space(3))) void* las_vp;

__device__ __forceinline__ void gload_lds16(const void* g, void* l) {
  __builtin_amdgcn_global_load_lds((gas_cvp)g, (las_vp)l, 16, 0, 0);
}

__device__ __forceinline__ short f2bf(float f) {
  __hip_bfloat16 h = __float2bfloat16(f);
  return *reinterpret_cast<short*>(&h);
}
__device__ __forceinline__ float bf2f(short s) {
  unsigned u = ((unsigned)(unsigned short)s) << 16;
  return __builtin_bit_cast(float, u);
}

#if __has_builtin(__builtin_amdgcn_exp2f)
#define EXP2(x) __builtin_amdgcn_exp2f(x)
#else
#define EXP2(x) exp2f(x)
#endif

constexpr int BATCH = 2;
constexpr int SEQ   = 2048;
constexpr int NH    = 16;
constexpr int MROWS = BATCH * SEQ;   // 4096
constexpr int NSPLIT = 4;            // K-direction split for occupancy
constexpr int KSPL   = SEQ / NSPLIT; // keys per split = 512
constexpr int RH     = MROWS * NH;   // rowheads = 65536

// ------------------------------- small kernels -----------------------------

__global__ __launch_bounds__(256) void cvt_bf16(const float* __restrict__ src,
                                                short* __restrict__ dst, int n4) {
  int i = blockIdx.x * 256 + threadIdx.x;
  if (i >= n4) return;
  float4 v = reinterpret_cast<const float4*>(src)[i];
  short4 o;
  o.x = f2bf(v.x); o.y = f2bf(v.y); o.z = f2bf(v.z); o.w = f2bf(v.w);
  reinterpret_cast<short4*>(dst)[i] = o;
}

// six 1024x1024 fp32->bf16 transposes in one launch (blockIdx.z selects)
struct WtA {
  const float* s[6];
  short* d[6];
  int st[6];
};
__global__ __launch_bounds__(256) void wtrans6(WtA a) {
  __shared__ float tile[32][33];
  const float* __restrict__ src = a.s[blockIdx.z];
  short* __restrict__ dst = a.d[blockIdx.z];
  const int stride = a.st[blockIdx.z];
  const int tx = threadIdx.x & 31, ty = threadIdx.x >> 5;   // 32 x 8
  const int n0 = blockIdx.x * 32, k0 = blockIdx.y * 32;
  #pragma unroll
  for (int i = 0; i < 32; i += 8)
    tile[ty + i][tx] = src[(size_t)(k0 + ty + i) * stride + n0 + tx];
  __syncthreads();
  #pragma unroll
  for (int i = 0; i < 32; i += 8)
    dst[(size_t)(n0 + ty + i) * 1024 + k0 + tx] = f2bf(tile[tx][ty + i]);
}

// V-part of QKV [4096][3072] (cols 2048..3071) -> VT [2][1024][2048] bf16
__global__ __launch_bounds__(256) void vtrans(const short* __restrict__ qkv,
                                              short* __restrict__ vt) {
  __shared__ short tile[32][33];
  const int tx = threadIdx.x & 31, ty = threadIdx.x >> 5;
  const int s0 = blockIdx.x * 32, d0 = blockIdx.y * 32, b = blockIdx.z;
  #pragma unroll
  for (int i = 0; i < 32; i += 8)
    tile[ty + i][tx] = qkv[(size_t)(b * SEQ + s0 + ty + i) * 3072 + 2048 + d0 + tx];
  __syncthreads();
  #pragma unroll
  for (int i = 0; i < 32; i += 8)
    vt[(size_t)(b * 1024 + d0 + ty + i) * SEQ + s0 + tx] = tile[tx][ty + i];
}

// bqkv = [bq|bkv] (3072), b12 = [b1|b2] (2048) in one launch (grid 20)
__global__ void pack_bias(const float* __restrict__ bq, const float* __restrict__ bkv,
                          const float* __restrict__ b1, const float* __restrict__ b2,
                          float* __restrict__ bqkv, float* __restrict__ b12) {
  int i = blockIdx.x * 256 + threadIdx.x;
  if (i < 1024) bqkv[i] = bq[i];
  else if (i < 3072) bqkv[i] = bkv[i - 1024];
  else if (i < 4096) b12[i - 3072] = b1[i - 3072];
  else if (i < 5120) b12[i - 3072] = b2[i - 4096];
}

__device__ __forceinline__ bool mask_at(const void* mp, int idx, int flag) {
  if (flag == 1) return ((const int*)mp)[idx] != 0;
  if (flag == 2) return ((const float*)mp)[idx] != 0.f;
  return ((const unsigned char*)mp)[idx] != 0;
}

// mask -> additive bias in exp2 domain, with inline dtype detection (mask bool
// may arrive as u8 / i32 / f32; each block re-detects from the first 4KB —
// L2-hot, cheap). Static-max softmax: fixed -8 shift folded in (cancels in O/s).
__global__ __launch_bounds__(256) void premask(const void* __restrict__ msk,
                                               float* __restrict__ mbL) {
  __shared__ int si, sf;
  const unsigned* m = (const unsigned*)msk;
  if (threadIdx.x == 0) { si = 1; sf = 1; }
  __syncthreads();
  bool oki = true, okf = true;
  for (int i = threadIdx.x; i < 1024; i += 256) {   // first 4096 bytes, in-bounds always
    unsigned v = m[i];
    oki = oki && (v <= 1u);
    okf = okf && (v == 0u || v == 0x3F800000u);
  }
  if (!oki) si = 0;
  if (!okf) sf = 0;
  __syncthreads();
  const int flag = si ? 1 : (sf ? 2 : 0);
  int i = blockIdx.x * 256 + threadIdx.x;
  if (i < MROWS) mbL[i] = mask_at(msk, i, flag) ? -1.442695e9f : -8.0f;
}

// ------------------------------- GEMM --------------------------------------
// C[M][N] = A[M][1024] @ BT[N][1024]^T + bias, M=4096, K=1024 fixed, bf16 out.
// T3-minimum 2-phase: double-buffered LDS, stage(t+1) issued BEFORE compute(t),
// one vmcnt(0)+barrier per K-step.
__global__ __launch_bounds__(256) void gemm_kernel(const short* __restrict__ A,
                                                   const short* __restrict__ BT,
                                                   const float* __restrict__ bias,
                                                   short* __restrict__ outp, int N) {
  __shared__ short Alds[2][4096];   // [128][32] x2
  __shared__ short Blds[2][4096];
  const int tid = threadIdx.x;
  const int w = tid >> 6, lane = tid & 63, g = lane >> 4, lr = lane & 15;
  const int wr = w >> 1, wc = w & 1;
  const int bm = blockIdx.y, bn = blockIdx.x;

  f32x4 acc[4][4] = {};

  const int srow = tid >> 2;          // 0..63
  const int scol = (tid & 3) * 8;     // 0,8,16,24
  const short* Ab = A  + (size_t)(bm * 128 + srow) * 1024 + scol;
  const short* Bb = BT + (size_t)(bn * 128 + srow) * 1024 + scol;

  auto stage = [&](int buf, int kt) {
    const int kb = kt * 32;
    gload_lds16(Ab + kb,             &Alds[buf][tid * 8]);
    gload_lds16(Ab + 64 * 1024 + kb, &Alds[buf][2048 + tid * 8]);
    gload_lds16(Bb + kb,             &Blds[buf][tid * 8]);
    gload_lds16(Bb + 64 * 1024 + kb, &Blds[buf][2048 + tid * 8]);
  };

  stage(0, 0);
  asm volatile("s_waitcnt vmcnt(0)" ::: "memory");
  __syncthreads();

  for (int kt = 0; kt < 32; ++kt) {
    const int cur = kt & 1;
    if (kt + 1 < 32) stage(cur ^ 1, kt + 1);   // in flight across compute

    bf16x8 af[4], bfr[4];
    #pragma unroll
    for (int m = 0; m < 4; ++m)
      af[m] = *reinterpret_cast<const bf16x8*>(&Alds[cur][(wr * 64 + m * 16 + lr) * 32 + g * 8]);
    #pragma unroll
    for (int n = 0; n < 4; ++n)
      bfr[n] = *reinterpret_cast<const bf16x8*>(&Blds[cur][(wc * 64 + n * 16 + lr) * 32 + g * 8]);
    #pragma unroll
    for (int m = 0; m < 4; ++m)
      #pragma unroll
      for (int n = 0; n < 4; ++n)
        acc[m][n] = __builtin_amdgcn_mfma_f32_16x16x32_bf16(af[m], bfr[n], acc[m][n], 0, 0, 0);

    // next tile landed + all waves done reading cur
    asm volatile("s_waitcnt vmcnt(0)" ::: "memory");
    __syncthreads();
  }

  #pragma unroll
  for (int m = 0; m < 4; ++m) {
    const int row = bm * 128 + wr * 64 + m * 16 + g * 4;
    #pragma unroll
    for (int n = 0; n < 4; ++n) {
      const int col = bn * 128 + wc * 64 + n * 16 + lr;
      const float bv = bias[col];
      #pragma unroll
      for (int r = 0; r < 4; ++r)
        outp[(size_t)(row + r) * N + col] = f2bf(acc[m][n][r] + bv);
    }
  }
}

// GLU: g = sigmoid(x1) * x2,  x12 = [4096][2048] bf16 (x1 | x2), bf16 out
__global__ __launch_bounds__(256) void glu_kernel(const short* __restrict__ x12,
                                                  short* __restrict__ g) {
  const int i = blockIdx.x * 256 + threadIdx.x;   // over 4096*1024/8
  const int row = i >> 7, c8 = (i & 127) * 8;
  const size_t base = (size_t)row * 2048 + c8;
  bf16x8 a = *reinterpret_cast<const bf16x8*>(&x12[base]);
  bf16x8 b = *reinterpret_cast<const bf16x8*>(&x12[base + 1024]);
  bf16x8 r;
  #pragma unroll
  for (int j = 0; j < 8; ++j) {
    const float x = bf2f(a[j]);
    r[j] = f2bf(bf2f(b[j]) / (1.f + __expf(-x)));
  }
  *reinterpret_cast<bf16x8*>(&g[(size_t)row * 1024 + c8]) = r;
}

// ------------------------------- attention v7 -------------------------------
// Swapped-operand 32x32x16, 4-way K-split, KB=64, SINGLE-buffer granule-padded
// LDS (18.9KB -> residency reg-capped at ~4 blocks/CU, 2x v6) with T14 split
// staging: loadTile(t+1) global->reg BEFORE compute(t) (loads in flight under
// compute), ds_write after the barrier.  Conflict-free frag reads with
// compile-time immediate offsets.  Static-max softmax, permlane32_swap.
constexpr int KB = 64;               // keys per tile
constexpr int KSLOT = 8 * 66;        // K granule-major [8][66] 16B slots
constexpr int VSLOT = 8 * 66;        // V^T granule-major [8][66]

__global__ __launch_bounds__(256) void attn_kernel(const short* __restrict__ qkv,
                                                   const short* __restrict__ vt,
                                                   const float* __restrict__ mbL,
                                                   short* __restrict__ opart,
                                                   float* __restrict__ spart) {
  __shared__ short Kl[KSLOT * 8];   // 8.25 KB
  __shared__ short Vl[VSLOT * 8];   // 8.25 KB
  __shared__ float mb[KSPL];        // 2 KB mask bias (log2 domain, -8 shift)

  const int tid = threadIdx.x;
  const int w = tid >> 6, lane = tid & 63, ql = lane & 31, hi = lane >> 5;
  const int sp = blockIdx.x & (NSPLIT - 1), qb = blockIdx.x / NSPLIT;
  const int h = blockIdx.y, b = blockIdx.z;
  const int qrow = qb * 128 + w * 32 + ql;
  const int kofs = sp * KSPL;

  // ---- hoist Q fragments (B-operand: lane q holds Q[q][c*16 + hi*8 + j]) ----
  bf16x8 qf[4];
  {
    const short* qp = qkv + (size_t)(b * SEQ + qrow) * 3072 + h * 64;
    #pragma unroll
    for (int c = 0; c < 4; ++c)
      qf[c] = *reinterpret_cast<const bf16x8*>(qp + c * 16 + hi * 8);
  }

  // ---- staging maps (per-thread constants) ----
  // K: row r*32+(tid>>3), granule tid&7 -> slot (tid&7)*66 + row
  // V: drow r*32+(tid>>3), granule tid&7 -> slot (tid&7)*66 + drow
  const short* gkbase = qkv + (size_t)(b * SEQ + kofs) * 3072 + 1024 + h * 64
                        + (size_t)(tid >> 3) * 3072 + (tid & 7) * 8;
  const short* gvbase = vt + ((size_t)(b * 1024 + h * 64) + (tid >> 3)) * SEQ + kofs
                        + (tid & 7) * 8;
  short* kwr = &Kl[((tid & 7) * 66 + (tid >> 3)) * 8];
  short* vwr = &Vl[((tid & 7) * 66 + (tid >> 3)) * 8];

  u32x4 kreg0, kreg1, vreg0, vreg1;
  auto loadTile = [&](int kt) {
    const short* gk = gkbase + (size_t)kt * KB * 3072;
    kreg0 = *reinterpret_cast<const u32x4*>(gk);
    kreg1 = *reinterpret_cast<const u32x4*>(gk + 32 * 3072);
    const short* gv = gvbase + kt * KB;
    vreg0 = *reinterpret_cast<const u32x4*>(gv);
    vreg1 = *reinterpret_cast<const u32x4*>(gv + 32 * SEQ);
  };
  auto writeTile = [&]() {
    *reinterpret_cast<u32x4*>(kwr)          = kreg0;   // compiler waits vmcnt here
    *reinterpret_cast<u32x4*>(kwr + 32 * 8) = kreg1;
    *reinterpret_cast<u32x4*>(vwr)          = vreg0;
    *reinterpret_cast<u32x4*>(vwr + 32 * 8) = vreg1;
  };

  float s_run = 0.f;
  f32x16 oacc0 = {}, oacc1 = {};

  // ---- prologue: mask bias (2KB, waves 0-1) + tile 0 ----
  if (tid < 128) gload_lds16(mbL + b * SEQ + kofs + tid * 4, &mb[tid * 4]);
  loadTile(0);
  writeTile();
  __syncthreads();

  // per-lane LDS read bases (constant; reads use +imm offsets)
  const short* krd = &Kl[(hi * 66 + ql) * 8];    // + (c*2*66 + t2*32)*16B
  const short* vrd = &Vl[(hi * 66 + ql) * 8];    // + ((t2*4+ch*2)*66 (+32))*16B

  constexpr int NT = KSPL / KB;   // 8
  for (int kt = 0; kt < NT; ++kt) {
    if (kt + 1 < NT) loadTile(kt + 1);   // HBM latency hides under compute(t)

    #pragma unroll
    for (int t2 = 0; t2 < 2; ++t2) {
      // QK^T: S[k][q]
      f32x16 sc = {};
      __builtin_amdgcn_s_setprio(1);
      #pragma unroll
      for (int c = 0; c < 4; ++c) {
        bf16x8 kf = *reinterpret_cast<const bf16x8*>(krd + (c * 132 + t2 * 32) * 8);
        sc = __builtin_amdgcn_mfma_f32_32x32x16_bf16(kf, qf[c], sc, 0, 0, 0);
      }
      __builtin_amdgcn_s_setprio(0);
      // p = exp2(score*scale*log2e + bias)   (bias = mask? -1.4e9 : -8)
      float p[16];
      #pragma unroll
      for (int u = 0; u < 4; ++u) {
        float4 m4 = *reinterpret_cast<const float4*>(&mb[kt * KB + t2 * 32 + u * 8 + hi * 4]);
        p[4 * u + 0] = EXP2(fmaf(sc[4 * u + 0], 0.18033688f, m4.x));   // 0.125*log2e
        p[4 * u + 1] = EXP2(fmaf(sc[4 * u + 1], 0.18033688f, m4.y));
        p[4 * u + 2] = EXP2(fmaf(sc[4 * u + 2], 0.18033688f, m4.z));
        p[4 * u + 3] = EXP2(fmaf(sc[4 * u + 3], 0.18033688f, m4.w));
      }
      // partial-sum tree (cross-lane deferred to epilogue)
      {
        float a0 = (p[0] + p[1]) + (p[2] + p[3]);
        float a1 = (p[4] + p[5]) + (p[6] + p[7]);
        float a2 = (p[8] + p[9]) + (p[10] + p[11]);
        float a3 = (p[12] + p[13]) + (p[14] + p[15]);
        s_run += (a0 + a1) + (a2 + a3);
      }
      // pack P -> bf16 pairs; permlane32_swap redistributes across half-waves
      unsigned P[8];
      #pragma unroll
      for (int j = 0; j < 8; ++j)
        asm("v_cvt_pk_bf16_f32 %0, %1, %2" : "=v"(P[j]) : "v"(p[2 * j]), "v"(p[2 * j + 1]));
      asm("v_permlane32_swap_b32 %0, %1" : "+v"(P[0]), "+v"(P[2]));
      asm("v_permlane32_swap_b32 %0, %1" : "+v"(P[1]), "+v"(P[3]));
      asm("v_permlane32_swap_b32 %0, %1" : "+v"(P[4]), "+v"(P[6]));
      asm("v_permlane32_swap_b32 %0, %1" : "+v"(P[5]), "+v"(P[7]));
      u32x4 c0 = { P[0], P[1], P[2], P[3] };
      u32x4 c1 = { P[4], P[5], P[6], P[7] };
      bf16x8 pf[2] = { __builtin_bit_cast(bf16x8, c0), __builtin_bit_cast(bf16x8, c1) };

      // PV: O^T[d][q] += V^T[d][k] P[k][q]
      __builtin_amdgcn_s_setprio(1);
      #pragma unroll
      for (int ch = 0; ch < 2; ++ch) {
        const int gb = (t2 * 4 + ch * 2) * 66;
        bf16x8 v0 = *reinterpret_cast<const bf16x8*>(vrd + gb * 8);
        bf16x8 v1 = *reinterpret_cast<const bf16x8*>(vrd + (gb + 32) * 8);
        oacc0 = __builtin_amdgcn_mfma_f32_32x32x16_bf16(v0, pf[ch], oacc0, 0, 0, 0);
        oacc1 = __builtin_amdgcn_mfma_f32_32x32x16_bf16(v1, pf[ch], oacc1, 0, 0, 0);
      }
      __builtin_amdgcn_s_setprio(0);
    }

    if (kt + 1 < NT) {
      __syncthreads();    // all waves done reading current tile
      writeTile();        // vmcnt wait ~0: loads had a full compute to land
      __syncthreads();    // writes visible
    }
  }

  // ---- epilogue: finish sum across half-waves, store unnormalized O + s ----
  const float sT = s_run + __shfl_xor(s_run, 32);
  const size_t obase = (size_t)sp * RH * 64 + (size_t)(b * SEQ + qrow) * 1024 + h * 64;
  #pragma unroll
  for (int dt = 0; dt < 2; ++dt) {
    #pragma unroll
    for (int u = 0; u < 4; ++u) {
      short4 st;
      const f32x16& oa = dt ? oacc1 : oacc0;
      st.x = f2bf(oa[4 * u + 0]);
      st.y = f2bf(oa[4 * u + 1]);
      st.z = f2bf(oa[4 * u + 2]);
      st.w = f2bf(oa[4 * u + 3]);
      *reinterpret_cast<short4*>(&opart[obase + dt * 32 + u * 8 + hi * 4]) = st;
    }
  }
  if (hi == 0)
    spart[sp * RH + (b * SEQ + qrow) * NH + h] = sT;
}

// merge K-splits: att = sum(O_s) / sum(s_s)   (same fixed shift cancels)
__global__ __launch_bounds__(256) void attn_merge(const short* __restrict__ opart,
                                                  const float* __restrict__ spart,
                                                  short* __restrict__ att) {
  const int idx = blockIdx.x * 256 + threadIdx.x;   // RH*8 = 524288
  const int rh = idx >> 3;
  const size_t base = (size_t)rh * 64 + (idx & 7) * 8;
  float acc[8] = {};
  float ss = 0.f;
  #pragma unroll
  for (int s = 0; s < NSPLIT; ++s) {
    bf16x8 o = *reinterpret_cast<const bf16x8*>(&opart[(size_t)s * RH * 64 + base]);
    #pragma unroll
    for (int j = 0; j < 8; ++j) acc[j] += bf2f(o[j]);
    ss += spart[s * RH + rh];
  }
  const float inv = 1.f / ss;
  bf16x8 r;
  #pragma unroll
  for (int j = 0; j < 8; ++j) r[j] = f2bf(acc[j] * inv);
  *reinterpret_cast<bf16x8*>(&att[base]) = r;
}

// -------------------------- residual + LayerNorm ----------------------------
__global__ __launch_bounds__(256) void ln_kernel(const float* __restrict__ h,
                                                 const short* __restrict__ ao,
                                                 const short* __restrict__ gl,
                                                 const float* __restrict__ gamma,
                                                 const float* __restrict__ beta,
                                                 float* __restrict__ out) {
  const int row = blockIdx.x;
  const size_t base = (size_t)row * 1024;
  const int t = threadIdx.x;
  __shared__ float red[4];
  float x[4];
  #pragma unroll
  for (int j = 0; j < 4; ++j) {
    const int c = t + j * 256;
    x[j] = h[base + c] + bf2f(ao[base + c]) + bf2f(gl[base + c]);
  }
  float s = x[0] + x[1] + x[2] + x[3];
  #pragma unroll
  for (int d = 1; d < 64; d <<= 1) s += __shfl_xor(s, d);
  if ((t & 63) == 0) red[t >> 6] = s;
  __syncthreads();
  const float mu = (red[0] + red[1] + red[2] + red[3]) * (1.f / 1024.f);
  __syncthreads();
  float vs = 0.f;
  #pragma unroll
  for (int j = 0; j < 4; ++j) { const float dx = x[j] - mu; vs += dx * dx; }
  #pragma unroll
  for (int d = 1; d < 64; d <<= 1) vs += __shfl_xor(vs, d);
  if ((t & 63) == 0) red[t >> 6] = vs;
  __syncthreads();
  const float var = (red[0] + red[1] + red[2] + red[3]) * (1.f / 1024.f);
  const float rs = rsqrtf(var + 1e-6f);
  #pragma unroll
  for (int j = 0; j < 4; ++j) {
    const int c = t + j * 256;
    out[base + c] = (x[j] - mu) * rs * gamma[c] + beta[c];
  }
}

// ------------------------------- launcher ----------------------------------

extern "C" void kernel_launch(void* const* d_in, const int* in_sizes, int n_in,
                              void* d_out, int out_size, void* d_ws, size_t ws_size,
                              hipStream_t stream) {
  const float* h   = (const float*)d_in[0];
  const void*  msk = d_in[1];
  const float* Wq  = (const float*)d_in[2];
  const float* bq  = (const float*)d_in[3];
  const float* Wkv = (const float*)d_in[4];
  const float* bkv = (const float*)d_in[5];
  const float* Wo  = (const float*)d_in[6];
  const float* bo  = (const float*)d_in[7];
  const float* W1  = (const float*)d_in[8];
  const float* b1  = (const float*)d_in[9];
  const float* W2  = (const float*)d_in[10];
  const float* b2  = (const float*)d_in[11];
  const float* lng = (const float*)d_in[12];
  const float* lnb = (const float*)d_in[13];
  float* out = (float*)d_out;

  char* ws = (char*)d_ws;
  size_t off = 0;
  auto alloc = [&](size_t bytes) {
    char* p = ws + off;
    off += (bytes + 255) & ~(size_t)255;
    return p;
  };
  short* X     = (short*)alloc((size_t)MROWS * 1024 * 2);   // h in bf16
  short* WqkvT = (short*)alloc((size_t)3072 * 1024 * 2);    // [Wq|Wkv]^T bf16
  short* WoT   = (short*)alloc((size_t)1024 * 1024 * 2);
  short* W1T   = (short*)alloc((size_t)1024 * 1024 * 2);
  short* W2T   = (short*)alloc((size_t)1024 * 1024 * 2);
  float* bqkv  = (float*)alloc(3072 * 4);
  float* b12   = (float*)alloc(2048 * 4);
  float* MBL   = (float*)alloc((size_t)MROWS * 4);          // mask bias (log2 dom)
  short* QKV   = (short*)alloc((size_t)MROWS * 3072 * 2);
  short* VT    = (short*)alloc((size_t)BATCH * 1024 * SEQ * 2);  // V transposed
  short* ATT   = (short*)alloc((size_t)MROWS * 1024 * 2);
  short* X1    = (short*)alloc((size_t)MROWS * 1024 * 2);   // GLU result bf16
  short* AO    = (short*)alloc((size_t)MROWS * 1024 * 2);   // attention proj bf16
  short* OP    = (short*)alloc((size_t)NSPLIT * RH * 64 * 2);  // partial O (unnorm)
  float* SP    = (float*)alloc((size_t)NSPLIT * RH * 4);       // partial sums
  short* X12   = OP;   // alias: OP (33.5MB) dead after merge; X12 needs 16.8MB
  if (off > ws_size) return;  // workspace too small: bail visibly

  cvt_bf16<<<4096, 256, 0, stream>>>(h, X, MROWS * 1024 / 4);
  WtA wa;
  wa.s[0] = Wq;          wa.d[0] = WqkvT;                wa.st[0] = 1024;
  wa.s[1] = Wkv;         wa.d[1] = WqkvT + 1024 * 1024;  wa.st[1] = 2048;
  wa.s[2] = Wkv + 1024;  wa.d[2] = WqkvT + 2048 * 1024;  wa.st[2] = 2048;
  wa.s[3] = Wo;          wa.d[3] = WoT;                  wa.st[3] = 1024;
  wa.s[4] = W1;          wa.d[4] = W1T;                  wa.st[4] = 1024;
  wa.s[5] = W2;          wa.d[5] = W2T;                  wa.st[5] = 1024;
  wtrans6<<<dim3(32, 32, 6), 256, 0, stream>>>(wa);
  pack_bias<<<20, 256, 0, stream>>>(bq, bkv, b1, b2, bqkv, b12);
  premask<<<16, 256, 0, stream>>>(msk, MBL);

  // QKV projection: [4096][3072] bf16
  gemm_kernel<<<dim3(24, 32), 256, 0, stream>>>(X, WqkvT, bqkv, QKV, 3072);
  // V transpose for attention A-operand
  vtrans<<<dim3(64, 32, 2), 256, 0, stream>>>(QKV, VT);
  // flash attention, 4-way K-split -> partials, then merge -> ATT
  attn_kernel<<<dim3(16 * NSPLIT, 16, 2), 256, 0, stream>>>(QKV, VT, MBL, OP, SP);
  attn_merge<<<RH * 8 / 256, 256, 0, stream>>>(OP, SP, ATT);
  // fused GLU GEMM: X12 = [X@W1+b1 | X@W2+b2] (bf16, aliases dead OP)
  gemm_kernel<<<dim3(16, 32), 256, 0, stream>>>(X, W1T, b12, X12, 2048);
  glu_kernel<<<MROWS * 1024 / 8 / 256, 256, 0, stream>>>(X12, X1);
  // attention out projection (bf16 out)
  gemm_kernel<<<dim3(8, 32), 256, 0, stream>>>(ATT, WoT, bo, AO, 1024);
  // out = LayerNorm(h + AO + X1)
  ln_kernel<<<MROWS, 256, 0, stream>>>(h, AO, X1, lng, lnb, out);
}

// Round 9
// 178.967 us; speedup vs baseline: 1.0806x; 1.0806x over previous
//
#include <hip/hip_runtime.h>
#include <hip/hip_bf16.h>

// ---------------------------------------------------------------------------
// Transformer block: LN(h + (softmax(mask(QK^T))V)Wo + sigmoid(hW1)*(hW2))
// B=2 S=2048 D_MODEL=1024 H=16 DH=64.  All heavy math in bf16 MFMA.
// ---------------------------------------------------------------------------

typedef short bf16x8 __attribute__((ext_vector_type(8)));   // 8 bf16 = 4 VGPR
typedef float f32x4  __attribute__((ext_vector_type(4)));
typedef float f32x16 __attribute__((ext_vector_type(16)));
typedef unsigned int u32x4 __attribute__((ext_vector_type(4)));

typedef const __attribute__((address_space(1))) void* gas_cvp;
typedef __attribute__((address_space(3))) void* las_vp;

__device__ __forceinline__ void gload_lds16(const void* g, void* l) {
  __builtin_amdgcn_global_load_lds((gas_cvp)g, (las_vp)l, 16, 0, 0);
}

__device__ __forceinline__ short f2bf(float f) {
  __hip_bfloat16 h = __float2bfloat16(f);
  return *reinterpret_cast<short*>(&h);
}
__device__ __forceinline__ float bf2f(short s) {
  unsigned u = ((unsigned)(unsigned short)s) << 16;
  return __builtin_bit_cast(float, u);
}

#if __has_builtin(__builtin_amdgcn_exp2f)
#define EXP2(x) __builtin_amdgcn_exp2f(x)
#else
#define EXP2(x) exp2f(x)
#endif

constexpr int BATCH = 2;
constexpr int SEQ   = 2048;
constexpr int NH    = 16;
constexpr int MROWS = BATCH * SEQ;   // 4096
constexpr int NSPLIT = 4;            // K-direction split for occupancy
constexpr int KSPL   = SEQ / NSPLIT; // keys per split = 512
constexpr int RH     = MROWS * NH;   // rowheads = 65536

// ------------------------------- small kernels -----------------------------

__global__ __launch_bounds__(256) void cvt_bf16(const float* __restrict__ src,
                                                short* __restrict__ dst, int n4) {
  int i = blockIdx.x * 256 + threadIdx.x;
  if (i >= n4) return;
  float4 v = reinterpret_cast<const float4*>(src)[i];
  short4 o;
  o.x = f2bf(v.x); o.y = f2bf(v.y); o.z = f2bf(v.z); o.w = f2bf(v.w);
  reinterpret_cast<short4*>(dst)[i] = o;
}

// six 1024x1024 fp32->bf16 transposes in one launch (blockIdx.z selects).
// dst row = n*mul + add  (mul=2 interleaves W1/W2 for the fused-GLU GEMM).
struct WtA {
  const float* s[6];
  short* d[6];
  int st[6];
  int mul[6];
  int add[6];
};
__global__ __launch_bounds__(256) void wtrans6(WtA a) {
  __shared__ float tile[32][33];
  const float* __restrict__ src = a.s[blockIdx.z];
  short* __restrict__ dst = a.d[blockIdx.z];
  const int stride = a.st[blockIdx.z];
  const int mul = a.mul[blockIdx.z], add = a.add[blockIdx.z];
  const int tx = threadIdx.x & 31, ty = threadIdx.x >> 5;   // 32 x 8
  const int n0 = blockIdx.x * 32, k0 = blockIdx.y * 32;
  #pragma unroll
  for (int i = 0; i < 32; i += 8)
    tile[ty + i][tx] = src[(size_t)(k0 + ty + i) * stride + n0 + tx];
  __syncthreads();
  #pragma unroll
  for (int i = 0; i < 32; i += 8)
    dst[(size_t)((n0 + ty + i) * mul + add) * 1024 + k0 + tx] = f2bf(tile[tx][ty + i]);
}

// V-part of QKV [4096][3072] (cols 2048..3071) -> VT [2][1024][2048] bf16
__global__ __launch_bounds__(256) void vtrans(const short* __restrict__ qkv,
                                              short* __restrict__ vt) {
  __shared__ short tile[32][33];
  const int tx = threadIdx.x & 31, ty = threadIdx.x >> 5;
  const int s0 = blockIdx.x * 32, d0 = blockIdx.y * 32, b = blockIdx.z;
  #pragma unroll
  for (int i = 0; i < 32; i += 8)
    tile[ty + i][tx] = qkv[(size_t)(b * SEQ + s0 + ty + i) * 3072 + 2048 + d0 + tx];
  __syncthreads();
  #pragma unroll
  for (int i = 0; i < 32; i += 8)
    vt[(size_t)(b * 1024 + d0 + ty + i) * SEQ + s0 + tx] = tile[tx][ty + i];
}

// bqkv = [bq|bkv] (3072), b12i = interleaved {b1[j],b2[j]} (2048)
__global__ void pack_bias(const float* __restrict__ bq, const float* __restrict__ bkv,
                          const float* __restrict__ b1, const float* __restrict__ b2,
                          float* __restrict__ bqkv, float* __restrict__ b12i) {
  int i = blockIdx.x * 256 + threadIdx.x;
  if (i < 1024) bqkv[i] = bq[i];
  else if (i < 3072) bqkv[i] = bkv[i - 1024];
  else if (i < 4096) {
    const int j = i - 3072;
    b12i[2 * j] = b1[j];
    b12i[2 * j + 1] = b2[j];
  }
}

__device__ __forceinline__ bool mask_at(const void* mp, int idx, int flag) {
  if (flag == 1) return ((const int*)mp)[idx] != 0;
  if (flag == 2) return ((const float*)mp)[idx] != 0.f;
  return ((const unsigned char*)mp)[idx] != 0;
}

// mask -> additive bias in exp2 domain, with inline dtype detection (mask bool
// may arrive as u8 / i32 / f32). Static-max softmax: fixed -8 shift folded in.
__global__ __launch_bounds__(256) void premask(const void* __restrict__ msk,
                                               float* __restrict__ mbL) {
  __shared__ int si, sf;
  const unsigned* m = (const unsigned*)msk;
  if (threadIdx.x == 0) { si = 1; sf = 1; }
  __syncthreads();
  bool oki = true, okf = true;
  for (int i = threadIdx.x; i < 1024; i += 256) {   // first 4096 bytes, in-bounds always
    unsigned v = m[i];
    oki = oki && (v <= 1u);
    okf = okf && (v == 0u || v == 0x3F800000u);
  }
  if (!oki) si = 0;
  if (!okf) sf = 0;
  __syncthreads();
  const int flag = si ? 1 : (sf ? 2 : 0);
  int i = blockIdx.x * 256 + threadIdx.x;
  if (i < MROWS) mbL[i] = mask_at(msk, i, flag) ? -1.442695e9f : -8.0f;
}

// ------------------------------- GEMM --------------------------------------
// C[M][N] = A[M][1024] @ BT[N][1024]^T + bias, M=4096, K=1024, m97 structure
// (single-buffer LDS + global_load_lds; proven fastest form R6).
// EPI 0: bf16 out.  EPI 1: fused GLU — BT rows interleaved {W1,W2}; even lanes
// write sigmoid(x1)*x2 to out[row][col>>1] (bf16, N_out = N/2).
template <int EPI>
__global__ __launch_bounds__(256) void gemm_kernel(const short* __restrict__ A,
                                                   const short* __restrict__ BT,
                                                   const float* __restrict__ bias,
                                                   short* __restrict__ outp, int N) {
  __shared__ short Alds[4096];   // [128][32]
  __shared__ short Blds[4096];   // [128][32]
  const int tid = threadIdx.x;
  const int w = tid >> 6, lane = tid & 63, g = lane >> 4, lr = lane & 15;
  const int wr = w >> 1, wc = w & 1;
  const int bm = blockIdx.y, bn = blockIdx.x;

  f32x4 acc[4][4] = {};

  const int srow = tid >> 2;          // 0..63
  const int scol = (tid & 3) * 8;     // 0,8,16,24
  const short* Ab = A  + (size_t)(bm * 128 + srow) * 1024 + scol;
  const short* Bb = BT + (size_t)(bn * 128 + srow) * 1024 + scol;

  for (int kt = 0; kt < 32; ++kt) {
    const int kb = kt * 32;
    __syncthreads();
    gload_lds16(Ab + kb,             &Alds[tid * 8]);
    gload_lds16(Ab + 64 * 1024 + kb, &Alds[2048 + tid * 8]);
    gload_lds16(Bb + kb,             &Blds[tid * 8]);
    gload_lds16(Bb + 64 * 1024 + kb, &Blds[2048 + tid * 8]);
    asm volatile("s_waitcnt vmcnt(0)" ::: "memory");
    __syncthreads();

    bf16x8 af[4], bfr[4];
    #pragma unroll
    for (int m = 0; m < 4; ++m)
      af[m] = *reinterpret_cast<const bf16x8*>(&Alds[(wr * 64 + m * 16 + lr) * 32 + g * 8]);
    #pragma unroll
    for (int n = 0; n < 4; ++n)
      bfr[n] = *reinterpret_cast<const bf16x8*>(&Blds[(wc * 64 + n * 16 + lr) * 32 + g * 8]);
    #pragma unroll
    for (int m = 0; m < 4; ++m)
      #pragma unroll
      for (int n = 0; n < 4; ++n)
        acc[m][n] = __builtin_amdgcn_mfma_f32_16x16x32_bf16(af[m], bfr[n], acc[m][n], 0, 0, 0);
  }

  #pragma unroll
  for (int m = 0; m < 4; ++m) {
    const int row = bm * 128 + wr * 64 + m * 16 + g * 4;
    #pragma unroll
    for (int n = 0; n < 4; ++n) {
      const int col = bn * 128 + wc * 64 + n * 16 + lr;
      const float bv = bias[col];
      #pragma unroll
      for (int r = 0; r < 4; ++r) {
        const float v = acc[m][n][r] + bv;
        if constexpr (EPI == 0) {
          outp[(size_t)(row + r) * N + col] = f2bf(v);
        } else {
          // col parity == lane parity: even lane holds x1, odd neighbor x2
          const float vp = __shfl_xor(v, 1);
          if (!(lr & 1))
            outp[(size_t)(row + r) * (N / 2) + (col >> 1)] =
                f2bf(vp / (1.f + __expf(-v)));
        }
      }
    }
  }
}

// ------------------------------- attention v8 -------------------------------
// Swapped-operand 32x32x16, 4-way K-split, KB=64, DOUBLE-buffer granule-padded
// LDS with reg staging and ONE barrier per tile:
//   loadTile(t+1) -> compute(cur) -> writeTile(cur^1) -> barrier.
// (cur^1's readers finished a full tile ago, so no pre-write barrier needed.)
// Conflict-free frag reads with compile-time immediate offsets.  Static-max
// softmax, permlane32_swap P redistribution, setprio on MFMA clusters.
constexpr int KB = 64;               // keys per tile
constexpr int KSLOT = 8 * 66;        // K granule-major [8][66] 16B slots
constexpr int VSLOT = 8 * 66;        // V^T granule-major [8][66]

__global__ __launch_bounds__(256) void attn_kernel(const short* __restrict__ qkv,
                                                   const short* __restrict__ vt,
                                                   const float* __restrict__ mbL,
                                                   short* __restrict__ opart,
                                                   float* __restrict__ spart) {
  __shared__ short Kl[2][KSLOT * 8];   // 2 x 8.25 KB
  __shared__ short Vl[2][VSLOT * 8];   // 2 x 8.25 KB
  __shared__ float mb[KSPL];           // 2 KB mask bias (log2 domain, -8 shift)

  const int tid = threadIdx.x;
  const int w = tid >> 6, lane = tid & 63, ql = lane & 31, hi = lane >> 5;
  const int sp = blockIdx.x & (NSPLIT - 1), qb = blockIdx.x / NSPLIT;
  const int h = blockIdx.y, b = blockIdx.z;
  const int qrow = qb * 128 + w * 32 + ql;
  const int kofs = sp * KSPL;

  // ---- hoist Q fragments (B-operand: lane q holds Q[q][c*16 + hi*8 + j]) ----
  bf16x8 qf[4];
  {
    const short* qp = qkv + (size_t)(b * SEQ + qrow) * 3072 + h * 64;
    #pragma unroll
    for (int c = 0; c < 4; ++c)
      qf[c] = *reinterpret_cast<const bf16x8*>(qp + c * 16 + hi * 8);
  }

  // ---- staging maps (per-thread constants) ----
  const short* gkbase = qkv + (size_t)(b * SEQ + kofs) * 3072 + 1024 + h * 64
                        + (size_t)(tid >> 3) * 3072 + (tid & 7) * 8;
  const short* gvbase = vt + ((size_t)(b * 1024 + h * 64) + (tid >> 3)) * SEQ + kofs
                        + (tid & 7) * 8;
  short* kwr = &Kl[0][((tid & 7) * 66 + (tid >> 3)) * 8];
  short* vwr = &Vl[0][((tid & 7) * 66 + (tid >> 3)) * 8];

  u32x4 kreg0, kreg1, vreg0, vreg1;
  auto loadTile = [&](int kt) {
    const short* gk = gkbase + (size_t)kt * KB * 3072;
    kreg0 = *reinterpret_cast<const u32x4*>(gk);
    kreg1 = *reinterpret_cast<const u32x4*>(gk + 32 * 3072);
    const short* gv = gvbase + kt * KB;
    vreg0 = *reinterpret_cast<const u32x4*>(gv);
    vreg1 = *reinterpret_cast<const u32x4*>(gv + 32 * SEQ);
  };
  auto writeTile = [&](int buf) {
    short* kd = kwr + buf * KSLOT * 8;
    *reinterpret_cast<u32x4*>(kd)          = kreg0;   // compiler waits vmcnt here
    *reinterpret_cast<u32x4*>(kd + 32 * 8) = kreg1;
    short* vd = vwr + buf * VSLOT * 8;
    *reinterpret_cast<u32x4*>(vd)          = vreg0;
    *reinterpret_cast<u32x4*>(vd + 32 * 8) = vreg1;
  };

  float s_run = 0.f;
  f32x16 oacc0 = {}, oacc1 = {};

  // ---- prologue: mask bias (2KB, waves 0-1) + tile 0 ----
  if (tid < 128) gload_lds16(mbL + b * SEQ + kofs + tid * 4, &mb[tid * 4]);
  loadTile(0);
  writeTile(0);
  __syncthreads();

  // per-lane LDS read bases (constant; reads use +imm offsets)
  const short* krd = &Kl[0][(hi * 66 + ql) * 8];
  const short* vrd = &Vl[0][(hi * 66 + ql) * 8];

  constexpr int NT = KSPL / KB;   // 8
  for (int kt = 0; kt < NT; ++kt) {
    const int cur = kt & 1;
    if (kt + 1 < NT) loadTile(kt + 1);   // HBM latency hides under compute(t)
    const short* Kb = krd + cur * KSLOT * 8;
    const short* Vb = vrd + cur * VSLOT * 8;

    #pragma unroll
    for (int t2 = 0; t2 < 2; ++t2) {
      // QK^T: S[k][q]
      f32x16 sc = {};
      __builtin_amdgcn_s_setprio(1);
      #pragma unroll
      for (int c = 0; c < 4; ++c) {
        bf16x8 kf = *reinterpret_cast<const bf16x8*>(Kb + (c * 132 + t2 * 32) * 8);
        sc = __builtin_amdgcn_mfma_f32_32x32x16_bf16(kf, qf[c], sc, 0, 0, 0);
      }
      __builtin_amdgcn_s_setprio(0);
      // p = exp2(score*scale*log2e + bias)   (bias = mask? -1.4e9 : -8)
      float p[16];
      #pragma unroll
      for (int u = 0; u < 4; ++u) {
        float4 m4 = *reinterpret_cast<const float4*>(&mb[kt * KB + t2 * 32 + u * 8 + hi * 4]);
        p[4 * u + 0] = EXP2(fmaf(sc[4 * u + 0], 0.18033688f, m4.x));   // 0.125*log2e
        p[4 * u + 1] = EXP2(fmaf(sc[4 * u + 1], 0.18033688f, m4.y));
        p[4 * u + 2] = EXP2(fmaf(sc[4 * u + 2], 0.18033688f, m4.z));
        p[4 * u + 3] = EXP2(fmaf(sc[4 * u + 3], 0.18033688f, m4.w));
      }
      // partial-sum tree (cross-lane deferred to epilogue)
      {
        float a0 = (p[0] + p[1]) + (p[2] + p[3]);
        float a1 = (p[4] + p[5]) + (p[6] + p[7]);
        float a2 = (p[8] + p[9]) + (p[10] + p[11]);
        float a3 = (p[12] + p[13]) + (p[14] + p[15]);
        s_run += (a0 + a1) + (a2 + a3);
      }
      // pack P -> bf16 pairs; permlane32_swap redistributes across half-waves
      unsigned P[8];
      #pragma unroll
      for (int j = 0; j < 8; ++j)
        asm("v_cvt_pk_bf16_f32 %0, %1, %2" : "=v"(P[j]) : "v"(p[2 * j]), "v"(p[2 * j + 1]));
      asm("v_permlane32_swap_b32 %0, %1" : "+v"(P[0]), "+v"(P[2]));
      asm("v_permlane32_swap_b32 %0, %1" : "+v"(P[1]), "+v"(P[3]));
      asm("v_permlane32_swap_b32 %0, %1" : "+v"(P[4]), "+v"(P[6]));
      asm("v_permlane32_swap_b32 %0, %1" : "+v"(P[5]), "+v"(P[7]));
      u32x4 c0 = { P[0], P[1], P[2], P[3] };
      u32x4 c1 = { P[4], P[5], P[6], P[7] };
      bf16x8 pf[2] = { __builtin_bit_cast(bf16x8, c0), __builtin_bit_cast(bf16x8, c1) };

      // PV: O^T[d][q] += V^T[d][k] P[k][q]
      __builtin_amdgcn_s_setprio(1);
      #pragma unroll
      for (int ch = 0; ch < 2; ++ch) {
        const int gb = (t2 * 4 + ch * 2) * 66;
        bf16x8 v0 = *reinterpret_cast<const bf16x8*>(Vb + gb * 8);
        bf16x8 v1 = *reinterpret_cast<const bf16x8*>(Vb + (gb + 32) * 8);
        oacc0 = __builtin_amdgcn_mfma_f32_32x32x16_bf16(v0, pf[ch], oacc0, 0, 0, 0);
        oacc1 = __builtin_amdgcn_mfma_f32_32x32x16_bf16(v1, pf[ch], oacc1, 0, 0, 0);
      }
      __builtin_amdgcn_s_setprio(0);
    }

    if (kt + 1 < NT) {
      writeTile(cur ^ 1);   // cur^1 readers finished at end of tile kt-1
      __syncthreads();      // writes visible before tile kt+1 reads
    }
  }

  // ---- epilogue: finish sum across half-waves, store unnormalized O + s ----
  const float sT = s_run + __shfl_xor(s_run, 32);
  const size_t obase = (size_t)sp * RH * 64 + (size_t)(b * SEQ + qrow) * 1024 + h * 64;
  #pragma unroll
  for (int dt = 0; dt < 2; ++dt) {
    #pragma unroll
    for (int u = 0; u < 4; ++u) {
      short4 st;
      const f32x16& oa = dt ? oacc1 : oacc0;
      st.x = f2bf(oa[4 * u + 0]);
      st.y = f2bf(oa[4 * u + 1]);
      st.z = f2bf(oa[4 * u + 2]);
      st.w = f2bf(oa[4 * u + 3]);
      *reinterpret_cast<short4*>(&opart[obase + dt * 32 + u * 8 + hi * 4]) = st;
    }
  }
  if (hi == 0)
    spart[sp * RH + (b * SEQ + qrow) * NH + h] = sT;
}

// merge K-splits: att = sum(O_s) / sum(s_s)   (same fixed shift cancels)
__global__ __launch_bounds__(256) void attn_merge(const short* __restrict__ opart,
                                                  const float* __restrict__ spart,
                                                  short* __restrict__ att) {
  const int idx = blockIdx.x * 256 + threadIdx.x;   // RH*8 = 524288
  const int rh = idx >> 3;
  const size_t base = (size_t)rh * 64 + (idx & 7) * 8;
  float acc[8] = {};
  float ss = 0.f;
  #pragma unroll
  for (int s = 0; s < NSPLIT; ++s) {
    bf16x8 o = *reinterpret_cast<const bf16x8*>(&opart[(size_t)s * RH * 64 + base]);
    #pragma unroll
    for (int j = 0; j < 8; ++j) acc[j] += bf2f(o[j]);
    ss += spart[s * RH + rh];
  }
  const float inv = 1.f / ss;
  bf16x8 r;
  #pragma unroll
  for (int j = 0; j < 8; ++j) r[j] = f2bf(acc[j] * inv);
  *reinterpret_cast<bf16x8*>(&att[base]) = r;
}

// -------------------------- residual + LayerNorm ----------------------------
__global__ __launch_bounds__(256) void ln_kernel(const float* __restrict__ h,
                                                 const short* __restrict__ ao,
                                                 const short* __restrict__ gl,
                                                 const float* __restrict__ gamma,
                                                 const float* __restrict__ beta,
                                                 float* __restrict__ out) {
  const int row = blockIdx.x;
  const size_t base = (size_t)row * 1024;
  const int t = threadIdx.x;
  __shared__ float red[4];
  float x[4];
  #pragma unroll
  for (int j = 0; j < 4; ++j) {
    const int c = t + j * 256;
    x[j] = h[base + c] + bf2f(ao[base + c]) + bf2f(gl[base + c]);
  }
  float s = x[0] + x[1] + x[2] + x[3];
  #pragma unroll
  for (int d = 1; d < 64; d <<= 1) s += __shfl_xor(s, d);
  if ((t & 63) == 0) red[t >> 6] = s;
  __syncthreads();
  const float mu = (red[0] + red[1] + red[2] + red[3]) * (1.f / 1024.f);
  __syncthreads();
  float vs = 0.f;
  #pragma unroll
  for (int j = 0; j < 4; ++j) { const float dx = x[j] - mu; vs += dx * dx; }
  #pragma unroll
  for (int d = 1; d < 64; d <<= 1) vs += __shfl_xor(vs, d);
  if ((t & 63) == 0) red[t >> 6] = vs;
  __syncthreads();
  const float var = (red[0] + red[1] + red[2] + red[3]) * (1.f / 1024.f);
  const float rs = rsqrtf(var + 1e-6f);
  #pragma unroll
  for (int j = 0; j < 4; ++j) {
    const int c = t + j * 256;
    out[base + c] = (x[j] - mu) * rs * gamma[c] + beta[c];
  }
}

// ------------------------------- launcher ----------------------------------

extern "C" void kernel_launch(void* const* d_in, const int* in_sizes, int n_in,
                              void* d_out, int out_size, void* d_ws, size_t ws_size,
                              hipStream_t stream) {
  const float* h   = (const float*)d_in[0];
  const void*  msk = d_in[1];
  const float* Wq  = (const float*)d_in[2];
  const float* bq  = (const float*)d_in[3];
  const float* Wkv = (const float*)d_in[4];
  const float* bkv = (const float*)d_in[5];
  const float* Wo  = (const float*)d_in[6];
  const float* bo  = (const float*)d_in[7];
  const float* W1  = (const float*)d_in[8];
  const float* b1  = (const float*)d_in[9];
  const float* W2  = (const float*)d_in[10];
  const float* b2  = (const float*)d_in[11];
  const float* lng = (const float*)d_in[12];
  const float* lnb = (const float*)d_in[13];
  float* out = (float*)d_out;

  char* ws = (char*)d_ws;
  size_t off = 0;
  auto alloc = [&](size_t bytes) {
    char* p = ws + off;
    off += (bytes + 255) & ~(size_t)255;
    return p;
  };
  short* X     = (short*)alloc((size_t)MROWS * 1024 * 2);   // h in bf16
  short* WqkvT = (short*)alloc((size_t)3072 * 1024 * 2);    // [Wq|Wkv]^T bf16
  short* WoT   = (short*)alloc((size_t)1024 * 1024 * 2);
  short* W12T  = (short*)alloc((size_t)2048 * 1024 * 2);    // interleaved W1/W2^T
  float* bqkv  = (float*)alloc(3072 * 4);
  float* b12i  = (float*)alloc(2048 * 4);
  float* MBL   = (float*)alloc((size_t)MROWS * 4);          // mask bias (log2 dom)
  short* QKV   = (short*)alloc((size_t)MROWS * 3072 * 2);
  short* VT    = (short*)alloc((size_t)BATCH * 1024 * SEQ * 2);  // V transposed
  short* ATT   = (short*)alloc((size_t)MROWS * 1024 * 2);
  short* X1    = (short*)alloc((size_t)MROWS * 1024 * 2);   // GLU result bf16
  short* AO    = (short*)alloc((size_t)MROWS * 1024 * 2);   // attention proj bf16
  short* OP    = (short*)alloc((size_t)NSPLIT * RH * 64 * 2);  // partial O (unnorm)
  float* SP    = (float*)alloc((size_t)NSPLIT * RH * 4);       // partial sums
  if (off > ws_size) return;  // workspace too small: bail visibly

  cvt_bf16<<<4096, 256, 0, stream>>>(h, X, MROWS * 1024 / 4);
  WtA wa;
  wa.s[0] = Wq;          wa.d[0] = WqkvT;                wa.st[0] = 1024;  wa.mul[0] = 1; wa.add[0] = 0;
  wa.s[1] = Wkv;         wa.d[1] = WqkvT + 1024 * 1024;  wa.st[1] = 2048;  wa.mul[1] = 1; wa.add[1] = 0;
  wa.s[2] = Wkv + 1024;  wa.d[2] = WqkvT + 2048 * 1024;  wa.st[2] = 2048;  wa.mul[2] = 1; wa.add[2] = 0;
  wa.s[3] = Wo;          wa.d[3] = WoT;                  wa.st[3] = 1024;  wa.mul[3] = 1; wa.add[3] = 0;
  wa.s[4] = W1;          wa.d[4] = W12T;                 wa.st[4] = 1024;  wa.mul[4] = 2; wa.add[4] = 0;
  wa.s[5] = W2;          wa.d[5] = W12T;                 wa.st[5] = 1024;  wa.mul[5] = 2; wa.add[5] = 1;
  wtrans6<<<dim3(32, 32, 6), 256, 0, stream>>>(wa);
  pack_bias<<<16, 256, 0, stream>>>(bq, bkv, b1, b2, bqkv, b12i);
  premask<<<16, 256, 0, stream>>>(msk, MBL);

  // QKV projection: [4096][3072] bf16
  gemm_kernel<0><<<dim3(24, 32), 256, 0, stream>>>(X, WqkvT, bqkv, QKV, 3072);
  // V transpose for attention A-operand
  vtrans<<<dim3(64, 32, 2), 256, 0, stream>>>(QKV, VT);
  // flash attention, 4-way K-split -> partials, then merge -> ATT
  attn_kernel<<<dim3(16 * NSPLIT, 16, 2), 256, 0, stream>>>(QKV, VT, MBL, OP, SP);
  attn_merge<<<RH * 8 / 256, 256, 0, stream>>>(OP, SP, ATT);
  // fused GLU GEMM: X1 = sigmoid(X@W1+b1)*(X@W2+b2) directly (interleaved B)
  gemm_kernel<1><<<dim3(16, 32), 256, 0, stream>>>(X, W12T, b12i, X1, 2048);
  // attention out projection (bf16 out)
  gemm_kernel<0><<<dim3(8, 32), 256, 0, stream>>>(ATT, WoT, bo, AO, 1024);
  // out = LayerNorm(h + AO + X1)
  ln_kernel<<<MROWS, 256, 0, stream>>>(h, AO, X1, lng, lnb, out);
}

// Round 10
// 175.543 us; speedup vs baseline: 1.1017x; 1.0195x over previous
//
#include <hip/hip_runtime.h>
#include <hip/hip_bf16.h>

// ---------------------------------------------------------------------------
// Transformer block: LN(h + (softmax(mask(QK^T))V)Wo + sigmoid(hW1)*(hW2))
// B=2 S=2048 D_MODEL=1024 H=16 DH=64.  All heavy math in bf16 MFMA.
// ---------------------------------------------------------------------------

typedef short bf16x8 __attribute__((ext_vector_type(8)));   // 8 bf16 = 4 VGPR
typedef float f32x4  __attribute__((ext_vector_type(4)));
typedef float f32x16 __attribute__((ext_vector_type(16)));
typedef unsigned int u32x4 __attribute__((ext_vector_type(4)));

typedef const __attribute__((address_space(1))) void* gas_cvp;
typedef __attribute__((address_space(3))) void* las_vp;

__device__ __forceinline__ void gload_lds16(const void* g, void* l) {
  __builtin_amdgcn_global_load_lds((gas_cvp)g, (las_vp)l, 16, 0, 0);
}

__device__ __forceinline__ short f2bf(float f) {
  __hip_bfloat16 h = __float2bfloat16(f);
  return *reinterpret_cast<short*>(&h);
}
__device__ __forceinline__ float bf2f(short s) {
  unsigned u = ((unsigned)(unsigned short)s) << 16;
  return __builtin_bit_cast(float, u);
}

#if __has_builtin(__builtin_amdgcn_exp2f)
#define EXP2(x) __builtin_amdgcn_exp2f(x)
#else
#define EXP2(x) exp2f(x)
#endif

constexpr int BATCH = 2;
constexpr int SEQ   = 2048;
constexpr int NH    = 16;
constexpr int MROWS = BATCH * SEQ;   // 4096
constexpr int NSPLIT = 2;            // K-direction split for occupancy
constexpr int KSPL   = SEQ / NSPLIT; // keys per split = 1024
constexpr int RH     = MROWS * NH;   // rowheads = 65536

// ------------------------------- small kernels -----------------------------

__global__ __launch_bounds__(256) void cvt_bf16(const float* __restrict__ src,
                                                short* __restrict__ dst, int n4) {
  int i = blockIdx.x * 256 + threadIdx.x;
  if (i >= n4) return;
  float4 v = reinterpret_cast<const float4*>(src)[i];
  short4 o;
  o.x = f2bf(v.x); o.y = f2bf(v.y); o.z = f2bf(v.z); o.w = f2bf(v.w);
  reinterpret_cast<short4*>(dst)[i] = o;
}

// six 1024x1024 fp32->bf16 transposes in one launch (blockIdx.z selects).
// dst row = n*mul + add  (mul=2 interleaves W1/W2 for the fused-GLU GEMM).
struct WtA {
  const float* s[6];
  short* d[6];
  int st[6];
  int mul[6];
  int add[6];
};
__global__ __launch_bounds__(256) void wtrans6(WtA a) {
  __shared__ float tile[32][33];
  const float* __restrict__ src = a.s[blockIdx.z];
  short* __restrict__ dst = a.d[blockIdx.z];
  const int stride = a.st[blockIdx.z];
  const int mul = a.mul[blockIdx.z], add = a.add[blockIdx.z];
  const int tx = threadIdx.x & 31, ty = threadIdx.x >> 5;   // 32 x 8
  const int n0 = blockIdx.x * 32, k0 = blockIdx.y * 32;
  #pragma unroll
  for (int i = 0; i < 32; i += 8)
    tile[ty + i][tx] = src[(size_t)(k0 + ty + i) * stride + n0 + tx];
  __syncthreads();
  #pragma unroll
  for (int i = 0; i < 32; i += 8)
    dst[(size_t)((n0 + ty + i) * mul + add) * 1024 + k0 + tx] = f2bf(tile[tx][ty + i]);
}

// V-part of QKV [4096][3072] (cols 2048..3071) -> VT [2][1024][2048] bf16
__global__ __launch_bounds__(256) void vtrans(const short* __restrict__ qkv,
                                              short* __restrict__ vt) {
  __shared__ short tile[32][33];
  const int tx = threadIdx.x & 31, ty = threadIdx.x >> 5;
  const int s0 = blockIdx.x * 32, d0 = blockIdx.y * 32, b = blockIdx.z;
  #pragma unroll
  for (int i = 0; i < 32; i += 8)
    tile[ty + i][tx] = qkv[(size_t)(b * SEQ + s0 + ty + i) * 3072 + 2048 + d0 + tx];
  __syncthreads();
  #pragma unroll
  for (int i = 0; i < 32; i += 8)
    vt[(size_t)(b * 1024 + d0 + ty + i) * SEQ + s0 + tx] = tile[tx][ty + i];
}

// ball = [bq | bkv | interleaved {b1,b2}]  (5120 floats)
__global__ void pack_bias(const float* __restrict__ bq, const float* __restrict__ bkv,
                          const float* __restrict__ b1, const float* __restrict__ b2,
                          float* __restrict__ ball) {
  int i = blockIdx.x * 256 + threadIdx.x;
  if (i < 1024) ball[i] = bq[i];
  else if (i < 3072) ball[i] = bkv[i - 1024];
  else if (i < 4096) {
    const int j = i - 3072;
    ball[3072 + 2 * j] = b1[j];
    ball[3072 + 2 * j + 1] = b2[j];
  }
}

__device__ __forceinline__ bool mask_at(const void* mp, int idx, int flag) {
  if (flag == 1) return ((const int*)mp)[idx] != 0;
  if (flag == 2) return ((const float*)mp)[idx] != 0.f;
  return ((const unsigned char*)mp)[idx] != 0;
}

// mask -> additive bias in exp2 domain, with inline dtype detection (mask bool
// may arrive as u8 / i32 / f32). Static-max softmax: fixed -8 shift folded in.
__global__ __launch_bounds__(256) void premask(const void* __restrict__ msk,
                                               float* __restrict__ mbL) {
  __shared__ int si, sf;
  const unsigned* m = (const unsigned*)msk;
  if (threadIdx.x == 0) { si = 1; sf = 1; }
  __syncthreads();
  bool oki = true, okf = true;
  for (int i = threadIdx.x; i < 1024; i += 256) {   // first 4096 bytes, in-bounds always
    unsigned v = m[i];
    oki = oki && (v <= 1u);
    okf = okf && (v == 0u || v == 0x3F800000u);
  }
  if (!oki) si = 0;
  if (!okf) sf = 0;
  __syncthreads();
  const int flag = si ? 1 : (sf ? 2 : 0);
  int i = blockIdx.x * 256 + threadIdx.x;
  if (i < MROWS) mbL[i] = mask_at(msk, i, flag) ? -1.442695e9f : -8.0f;
}

// ------------------------------- GEMM --------------------------------------
// m97 structure (single-buffer LDS + global_load_lds), K=1024, M=4096.
// gemm_bf16<BN>: plain bf16 out, BN = 128 or 64 cols/block (64 -> 2x blocks
// for small-N shapes like Wo: fixes the 1-block/CU occupancy hole).
template <int BN>
__global__ __launch_bounds__(256) void gemm_bf16(const short* __restrict__ A,
                                                 const short* __restrict__ BT,
                                                 const float* __restrict__ bias,
                                                 short* __restrict__ outp, int N) {
  constexpr int NF = BN / 32;     // B-frags per wave (4 or 2)
  __shared__ short Alds[4096];    // [128][32]
  __shared__ short Blds[BN * 32];
  const int tid = threadIdx.x;
  const int w = tid >> 6, lane = tid & 63, g = lane >> 4, lr = lane & 15;
  const int wr = w >> 1, wc = w & 1;
  const int bm = blockIdx.y, bn = blockIdx.x;

  f32x4 acc[4][NF] = {};

  const int srow = tid >> 2;          // 0..63
  const int scol = (tid & 3) * 8;     // 0,8,16,24
  const short* Ab = A  + (size_t)(bm * 128 + srow) * 1024 + scol;
  const short* Bb = BT + (size_t)(bn * BN + srow) * 1024 + scol;

  for (int kt = 0; kt < 32; ++kt) {
    const int kb = kt * 32;
    __syncthreads();
    gload_lds16(Ab + kb,             &Alds[tid * 8]);
    gload_lds16(Ab + 64 * 1024 + kb, &Alds[2048 + tid * 8]);
    gload_lds16(Bb + kb,             &Blds[tid * 8]);
    if constexpr (BN == 128)
      gload_lds16(Bb + 64 * 1024 + kb, &Blds[2048 + tid * 8]);
    asm volatile("s_waitcnt vmcnt(0)" ::: "memory");
    __syncthreads();

    bf16x8 af[4], bfr[NF];
    #pragma unroll
    for (int m = 0; m < 4; ++m)
      af[m] = *reinterpret_cast<const bf16x8*>(&Alds[(wr * 64 + m * 16 + lr) * 32 + g * 8]);
    #pragma unroll
    for (int n = 0; n < NF; ++n)
      bfr[n] = *reinterpret_cast<const bf16x8*>(&Blds[(wc * (BN / 2) + n * 16 + lr) * 32 + g * 8]);
    #pragma unroll
    for (int m = 0; m < 4; ++m)
      #pragma unroll
      for (int n = 0; n < NF; ++n)
        acc[m][n] = __builtin_amdgcn_mfma_f32_16x16x32_bf16(af[m], bfr[n], acc[m][n], 0, 0, 0);
  }

  #pragma unroll
  for (int m = 0; m < 4; ++m) {
    const int row = bm * 128 + wr * 64 + m * 16 + g * 4;
    #pragma unroll
    for (int n = 0; n < NF; ++n) {
      const int col = bn * BN + wc * (BN / 2) + n * 16 + lr;
      const float bv = bias[col];
      #pragma unroll
      for (int r = 0; r < 4; ++r)
        outp[(size_t)(row + r) * N + col] = f2bf(acc[m][n][r] + bv);
    }
  }
}

// Fused QKV + GLU GEMM: B = [WqkvT (3072 rows) | W12T interleaved (2048 rows)],
// 5120 total, grid (40, 32).  bn<24 -> QKV bf16 out [4096][3072];
// bn>=24 -> GLU: even lanes write sigmoid(x1)*x2 to X1 [4096][1024].
__global__ __launch_bounds__(256) void gemm_qkvglu(const short* __restrict__ A,
                                                   const short* __restrict__ BT,
                                                   const float* __restrict__ bias,
                                                   short* __restrict__ qkv,
                                                   short* __restrict__ x1) {
  __shared__ short Alds[4096];
  __shared__ short Blds[4096];
  const int tid = threadIdx.x;
  const int w = tid >> 6, lane = tid & 63, g = lane >> 4, lr = lane & 15;
  const int wr = w >> 1, wc = w & 1;
  const int bm = blockIdx.y, bn = blockIdx.x;

  f32x4 acc[4][4] = {};

  const int srow = tid >> 2;
  const int scol = (tid & 3) * 8;
  const short* Ab = A  + (size_t)(bm * 128 + srow) * 1024 + scol;
  const short* Bb = BT + (size_t)(bn * 128 + srow) * 1024 + scol;

  for (int kt = 0; kt < 32; ++kt) {
    const int kb = kt * 32;
    __syncthreads();
    gload_lds16(Ab + kb,             &Alds[tid * 8]);
    gload_lds16(Ab + 64 * 1024 + kb, &Alds[2048 + tid * 8]);
    gload_lds16(Bb + kb,             &Blds[tid * 8]);
    gload_lds16(Bb + 64 * 1024 + kb, &Blds[2048 + tid * 8]);
    asm volatile("s_waitcnt vmcnt(0)" ::: "memory");
    __syncthreads();

    bf16x8 af[4], bfr[4];
    #pragma unroll
    for (int m = 0; m < 4; ++m)
      af[m] = *reinterpret_cast<const bf16x8*>(&Alds[(wr * 64 + m * 16 + lr) * 32 + g * 8]);
    #pragma unroll
    for (int n = 0; n < 4; ++n)
      bfr[n] = *reinterpret_cast<const bf16x8*>(&Blds[(wc * 64 + n * 16 + lr) * 32 + g * 8]);
    #pragma unroll
    for (int m = 0; m < 4; ++m)
      #pragma unroll
      for (int n = 0; n < 4; ++n)
        acc[m][n] = __builtin_amdgcn_mfma_f32_16x16x32_bf16(af[m], bfr[n], acc[m][n], 0, 0, 0);
  }

  const bool isGlu = (bn >= 24);
  #pragma unroll
  for (int m = 0; m < 4; ++m) {
    const int row = bm * 128 + wr * 64 + m * 16 + g * 4;
    #pragma unroll
    for (int n = 0; n < 4; ++n) {
      const int col = bn * 128 + wc * 64 + n * 16 + lr;
      const float bv = bias[col];
      #pragma unroll
      for (int r = 0; r < 4; ++r) {
        const float v = acc[m][n][r] + bv;
        if (!isGlu) {
          qkv[(size_t)(row + r) * 3072 + col] = f2bf(v);
        } else {
          // interleaved cols: even lane = x1, odd neighbor = x2
          const float vp = __shfl_xor(v, 1);
          if (!(lr & 1)) {
            const int col2 = col - 3072;
            x1[(size_t)(row + r) * 1024 + (col2 >> 1)] = f2bf(vp / (1.f + __expf(-v)));
          }
        }
      }
    }
  }
}

// ------------------------------- attention v8 -------------------------------
// Swapped-operand 32x32x16, 2-way K-split, KB=64, double-buffer granule-padded
// LDS with reg staging and ONE barrier per tile:
//   loadTile(t+1) -> compute(cur) -> writeTile(cur^1) -> barrier.
// Conflict-free frag reads with compile-time immediate offsets.  Static-max
// softmax, permlane32_swap P redistribution, setprio on MFMA clusters.
constexpr int KB = 64;               // keys per tile
constexpr int KSLOT = 8 * 66;        // K granule-major [8][66] 16B slots
constexpr int VSLOT = 8 * 66;        // V^T granule-major [8][66]

__global__ __launch_bounds__(256) void attn_kernel(const short* __restrict__ qkv,
                                                   const short* __restrict__ vt,
                                                   const float* __restrict__ mbL,
                                                   short* __restrict__ opart,
                                                   float* __restrict__ spart) {
  __shared__ short Kl[2][KSLOT * 8];   // 2 x 8.25 KB
  __shared__ short Vl[2][VSLOT * 8];   // 2 x 8.25 KB
  __shared__ float mb[KSPL];           // 4 KB mask bias (log2 domain, -8 shift)

  const int tid = threadIdx.x;
  const int w = tid >> 6, lane = tid & 63, ql = lane & 31, hi = lane >> 5;
  const int sp = blockIdx.x & (NSPLIT - 1), qb = blockIdx.x / NSPLIT;
  const int h = blockIdx.y, b = blockIdx.z;
  const int qrow = qb * 128 + w * 32 + ql;
  const int kofs = sp * KSPL;

  // ---- hoist Q fragments (B-operand: lane q holds Q[q][c*16 + hi*8 + j]) ----
  bf16x8 qf[4];
  {
    const short* qp = qkv + (size_t)(b * SEQ + qrow) * 3072 + h * 64;
    #pragma unroll
    for (int c = 0; c < 4; ++c)
      qf[c] = *reinterpret_cast<const bf16x8*>(qp + c * 16 + hi * 8);
  }

  // ---- staging maps (per-thread constants) ----
  const short* gkbase = qkv + (size_t)(b * SEQ + kofs) * 3072 + 1024 + h * 64
                        + (size_t)(tid >> 3) * 3072 + (tid & 7) * 8;
  const short* gvbase = vt + ((size_t)(b * 1024 + h * 64) + (tid >> 3)) * SEQ + kofs
                        + (tid & 7) * 8;
  short* kwr = &Kl[0][((tid & 7) * 66 + (tid >> 3)) * 8];
  short* vwr = &Vl[0][((tid & 7) * 66 + (tid >> 3)) * 8];

  u32x4 kreg0, kreg1, vreg0, vreg1;
  auto loadTile = [&](int kt) {
    const short* gk = gkbase + (size_t)kt * KB * 3072;
    kreg0 = *reinterpret_cast<const u32x4*>(gk);
    kreg1 = *reinterpret_cast<const u32x4*>(gk + 32 * 3072);
    const short* gv = gvbase + kt * KB;
    vreg0 = *reinterpret_cast<const u32x4*>(gv);
    vreg1 = *reinterpret_cast<const u32x4*>(gv + 32 * SEQ);
  };
  auto writeTile = [&](int buf) {
    short* kd = kwr + buf * KSLOT * 8;
    *reinterpret_cast<u32x4*>(kd)          = kreg0;   // compiler waits vmcnt here
    *reinterpret_cast<u32x4*>(kd + 32 * 8) = kreg1;
    short* vd = vwr + buf * VSLOT * 8;
    *reinterpret_cast<u32x4*>(vd)          = vreg0;
    *reinterpret_cast<u32x4*>(vd + 32 * 8) = vreg1;
  };

  float s_run = 0.f;
  f32x16 oacc0 = {}, oacc1 = {};

  // ---- prologue: mask bias (4KB, all waves) + tile 0 ----
  gload_lds16(mbL + b * SEQ + kofs + tid * 4, &mb[tid * 4]);
  loadTile(0);
  writeTile(0);
  __syncthreads();

  // per-lane LDS read bases (constant; reads use +imm offsets)
  const short* krd = &Kl[0][(hi * 66 + ql) * 8];
  const short* vrd = &Vl[0][(hi * 66 + ql) * 8];

  constexpr int NT = KSPL / KB;   // 16
  for (int kt = 0; kt < NT; ++kt) {
    const int cur = kt & 1;
    if (kt + 1 < NT) loadTile(kt + 1);   // HBM latency hides under compute(t)
    const short* Kb = krd + cur * KSLOT * 8;
    const short* Vb = vrd + cur * VSLOT * 8;

    #pragma unroll
    for (int t2 = 0; t2 < 2; ++t2) {
      // QK^T: S[k][q]
      f32x16 sc = {};
      __builtin_amdgcn_s_setprio(1);
      #pragma unroll
      for (int c = 0; c < 4; ++c) {
        bf16x8 kf = *reinterpret_cast<const bf16x8*>(Kb + (c * 132 + t2 * 32) * 8);
        sc = __builtin_amdgcn_mfma_f32_32x32x16_bf16(kf, qf[c], sc, 0, 0, 0);
      }
      __builtin_amdgcn_s_setprio(0);
      // p = exp2(score*scale*log2e + bias)   (bias = mask? -1.4e9 : -8)
      float p[16];
      #pragma unroll
      for (int u = 0; u < 4; ++u) {
        float4 m4 = *reinterpret_cast<const float4*>(&mb[kt * KB + t2 * 32 + u * 8 + hi * 4]);
        p[4 * u + 0] = EXP2(fmaf(sc[4 * u + 0], 0.18033688f, m4.x));   // 0.125*log2e
        p[4 * u + 1] = EXP2(fmaf(sc[4 * u + 1], 0.18033688f, m4.y));
        p[4 * u + 2] = EXP2(fmaf(sc[4 * u + 2], 0.18033688f, m4.z));
        p[4 * u + 3] = EXP2(fmaf(sc[4 * u + 3], 0.18033688f, m4.w));
      }
      // partial-sum tree (cross-lane deferred to epilogue)
      {
        float a0 = (p[0] + p[1]) + (p[2] + p[3]);
        float a1 = (p[4] + p[5]) + (p[6] + p[7]);
        float a2 = (p[8] + p[9]) + (p[10] + p[11]);
        float a3 = (p[12] + p[13]) + (p[14] + p[15]);
        s_run += (a0 + a1) + (a2 + a3);
      }
      // pack P -> bf16 pairs; permlane32_swap redistributes across half-waves
      unsigned P[8];
      #pragma unroll
      for (int j = 0; j < 8; ++j)
        asm("v_cvt_pk_bf16_f32 %0, %1, %2" : "=v"(P[j]) : "v"(p[2 * j]), "v"(p[2 * j + 1]));
      asm("v_permlane32_swap_b32 %0, %1" : "+v"(P[0]), "+v"(P[2]));
      asm("v_permlane32_swap_b32 %0, %1" : "+v"(P[1]), "+v"(P[3]));
      asm("v_permlane32_swap_b32 %0, %1" : "+v"(P[4]), "+v"(P[6]));
      asm("v_permlane32_swap_b32 %0, %1" : "+v"(P[5]), "+v"(P[7]));
      u32x4 c0 = { P[0], P[1], P[2], P[3] };
      u32x4 c1 = { P[4], P[5], P[6], P[7] };
      bf16x8 pf[2] = { __builtin_bit_cast(bf16x8, c0), __builtin_bit_cast(bf16x8, c1) };

      // PV: O^T[d][q] += V^T[d][k] P[k][q]
      __builtin_amdgcn_s_setprio(1);
      #pragma unroll
      for (int ch = 0; ch < 2; ++ch) {
        const int gb = (t2 * 4 + ch * 2) * 66;
        bf16x8 v0 = *reinterpret_cast<const bf16x8*>(Vb + gb * 8);
        bf16x8 v1 = *reinterpret_cast<const bf16x8*>(Vb + (gb + 32) * 8);
        oacc0 = __builtin_amdgcn_mfma_f32_32x32x16_bf16(v0, pf[ch], oacc0, 0, 0, 0);
        oacc1 = __builtin_amdgcn_mfma_f32_32x32x16_bf16(v1, pf[ch], oacc1, 0, 0, 0);
      }
      __builtin_amdgcn_s_setprio(0);
    }

    if (kt + 1 < NT) {
      writeTile(cur ^ 1);   // cur^1 readers finished at end of tile kt-1
      __syncthreads();      // writes visible before tile kt+1 reads
    }
  }

  // ---- epilogue: finish sum across half-waves, store unnormalized O + s ----
  const float sT = s_run + __shfl_xor(s_run, 32);
  const size_t obase = (size_t)sp * RH * 64 + (size_t)(b * SEQ + qrow) * 1024 + h * 64;
  #pragma unroll
  for (int dt = 0; dt < 2; ++dt) {
    #pragma unroll
    for (int u = 0; u < 4; ++u) {
      short4 st;
      const f32x16& oa = dt ? oacc1 : oacc0;
      st.x = f2bf(oa[4 * u + 0]);
      st.y = f2bf(oa[4 * u + 1]);
      st.z = f2bf(oa[4 * u + 2]);
      st.w = f2bf(oa[4 * u + 3]);
      *reinterpret_cast<short4*>(&opart[obase + dt * 32 + u * 8 + hi * 4]) = st;
    }
  }
  if (hi == 0)
    spart[sp * RH + (b * SEQ + qrow) * NH + h] = sT;
}

// merge K-splits: att = sum(O_s) / sum(s_s)   (same fixed shift cancels)
__global__ __launch_bounds__(256) void attn_merge(const short* __restrict__ opart,
                                                  const float* __restrict__ spart,
                                                  short* __restrict__ att) {
  const int idx = blockIdx.x * 256 + threadIdx.x;   // RH*8 = 524288
  const int rh = idx >> 3;
  const size_t base = (size_t)rh * 64 + (idx & 7) * 8;
  float acc[8] = {};
  float ss = 0.f;
  #pragma unroll
  for (int s = 0; s < NSPLIT; ++s) {
    bf16x8 o = *reinterpret_cast<const bf16x8*>(&opart[(size_t)s * RH * 64 + base]);
    #pragma unroll
    for (int j = 0; j < 8; ++j) acc[j] += bf2f(o[j]);
    ss += spart[s * RH + rh];
  }
  const float inv = 1.f / ss;
  bf16x8 r;
  #pragma unroll
  for (int j = 0; j < 8; ++j) r[j] = f2bf(acc[j] * inv);
  *reinterpret_cast<bf16x8*>(&att[base]) = r;
}

// -------------------------- residual + LayerNorm ----------------------------
__global__ __launch_bounds__(256) void ln_kernel(const float* __restrict__ h,
                                                 const short* __restrict__ ao,
                                                 const short* __restrict__ gl,
                                                 const float* __restrict__ gamma,
                                                 const float* __restrict__ beta,
                                                 float* __restrict__ out) {
  const int row = blockIdx.x;
  const size_t base = (size_t)row * 1024;
  const int t = threadIdx.x;
  __shared__ float red[4];
  float x[4];
  #pragma unroll
  for (int j = 0; j < 4; ++j) {
    const int c = t + j * 256;
    x[j] = h[base + c] + bf2f(ao[base + c]) + bf2f(gl[base + c]);
  }
  float s = x[0] + x[1] + x[2] + x[3];
  #pragma unroll
  for (int d = 1; d < 64; d <<= 1) s += __shfl_xor(s, d);
  if ((t & 63) == 0) red[t >> 6] = s;
  __syncthreads();
  const float mu = (red[0] + red[1] + red[2] + red[3]) * (1.f / 1024.f);
  __syncthreads();
  float vs = 0.f;
  #pragma unroll
  for (int j = 0; j < 4; ++j) { const float dx = x[j] - mu; vs += dx * dx; }
  #pragma unroll
  for (int d = 1; d < 64; d <<= 1) vs += __shfl_xor(vs, d);
  if ((t & 63) == 0) red[t >> 6] = vs;
  __syncthreads();
  const float var = (red[0] + red[1] + red[2] + red[3]) * (1.f / 1024.f);
  const float rs = rsqrtf(var + 1e-6f);
  #pragma unroll
  for (int j = 0; j < 4; ++j) {
    const int c = t + j * 256;
    out[base + c] = (x[j] - mu) * rs * gamma[c] + beta[c];
  }
}

// ------------------------------- launcher ----------------------------------

extern "C" void kernel_launch(void* const* d_in, const int* in_sizes, int n_in,
                              void* d_out, int out_size, void* d_ws, size_t ws_size,
                              hipStream_t stream) {
  const float* h   = (const float*)d_in[0];
  const void*  msk = d_in[1];
  const float* Wq  = (const float*)d_in[2];
  const float* bq  = (const float*)d_in[3];
  const float* Wkv = (const float*)d_in[4];
  const float* bkv = (const float*)d_in[5];
  const float* Wo  = (const float*)d_in[6];
  const float* bo  = (const float*)d_in[7];
  const float* W1  = (const float*)d_in[8];
  const float* b1  = (const float*)d_in[9];
  const float* W2  = (const float*)d_in[10];
  const float* b2  = (const float*)d_in[11];
  const float* lng = (const float*)d_in[12];
  const float* lnb = (const float*)d_in[13];
  float* out = (float*)d_out;

  char* ws = (char*)d_ws;
  size_t off = 0;
  auto alloc = [&](size_t bytes) {
    char* p = ws + off;
    off += (bytes + 255) & ~(size_t)255;
    return p;
  };
  short* X     = (short*)alloc((size_t)MROWS * 1024 * 2);   // h in bf16
  short* WALL  = (short*)alloc((size_t)5120 * 1024 * 2);    // [Wq|Wkv|W1/W2 ilv]^T
  short* WoT   = (short*)alloc((size_t)1024 * 1024 * 2);
  float* ball  = (float*)alloc(5120 * 4);
  float* MBL   = (float*)alloc((size_t)MROWS * 4);          // mask bias (log2 dom)
  short* QKV   = (short*)alloc((size_t)MROWS * 3072 * 2);
  short* VT    = (short*)alloc((size_t)BATCH * 1024 * SEQ * 2);  // V transposed
  short* ATT   = (short*)alloc((size_t)MROWS * 1024 * 2);
  short* X1    = (short*)alloc((size_t)MROWS * 1024 * 2);   // GLU result bf16
  short* AO    = (short*)alloc((size_t)MROWS * 1024 * 2);   // attention proj bf16
  short* OP    = (short*)alloc((size_t)NSPLIT * RH * 64 * 2);  // partial O (unnorm)
  float* SP    = (float*)alloc((size_t)NSPLIT * RH * 4);       // partial sums
  if (off > ws_size) return;  // workspace too small: bail visibly

  cvt_bf16<<<4096, 256, 0, stream>>>(h, X, MROWS * 1024 / 4);
  WtA wa;
  wa.s[0] = Wq;          wa.d[0] = WALL;                wa.st[0] = 1024;  wa.mul[0] = 1; wa.add[0] = 0;
  wa.s[1] = Wkv;         wa.d[1] = WALL + 1024 * 1024;  wa.st[1] = 2048;  wa.mul[1] = 1; wa.add[1] = 0;
  wa.s[2] = Wkv + 1024;  wa.d[2] = WALL + 2048 * 1024;  wa.st[2] = 2048;  wa.mul[2] = 1; wa.add[2] = 0;
  wa.s[3] = Wo;          wa.d[3] = WoT;                 wa.st[3] = 1024;  wa.mul[3] = 1; wa.add[3] = 0;
  wa.s[4] = W1;          wa.d[4] = WALL + 3072 * 1024;  wa.st[4] = 1024;  wa.mul[4] = 2; wa.add[4] = 0;
  wa.s[5] = W2;          wa.d[5] = WALL + 3072 * 1024;  wa.st[5] = 1024;  wa.mul[5] = 2; wa.add[5] = 1;
  wtrans6<<<dim3(32, 32, 6), 256, 0, stream>>>(wa);
  pack_bias<<<16, 256, 0, stream>>>(bq, bkv, b1, b2, ball);
  premask<<<16, 256, 0, stream>>>(msk, MBL);

  // fused QKV + GLU projection (one 1280-block dispatch)
  gemm_qkvglu<<<dim3(40, 32), 256, 0, stream>>>(X, WALL, ball, QKV, X1);
  // V transpose for attention A-operand
  vtrans<<<dim3(64, 32, 2), 256, 0, stream>>>(QKV, VT);
  // flash attention, 2-way K-split -> partials, then merge -> ATT
  attn_kernel<<<dim3(16 * NSPLIT, 16, 2), 256, 0, stream>>>(QKV, VT, MBL, OP, SP);
  attn_merge<<<RH * 8 / 256, 256, 0, stream>>>(OP, SP, ATT);
  // attention out projection: BN=64 tile -> 512 blocks (2/CU)
  gemm_bf16<64><<<dim3(16, 32), 256, 0, stream>>>(ATT, WoT, bo, AO, 1024);
  // out = LayerNorm(h + AO + X1)
  ln_kernel<<<MROWS, 256, 0, stream>>>(h, AO, X1, lng, lnb, out);
}

// Round 11
// 173.233 us; speedup vs baseline: 1.1164x; 1.0133x over previous
//
#include <hip/hip_runtime.h>
#include <hip/hip_bf16.h>

// ---------------------------------------------------------------------------
// Transformer block: LN(h + (softmax(mask(QK^T))V)Wo + sigmoid(hW1)*(hW2))
// B=2 S=2048 D_MODEL=1024 H=16 DH=64.  All heavy math in bf16 MFMA.
// ---------------------------------------------------------------------------

typedef short bf16x8 __attribute__((ext_vector_type(8)));   // 8 bf16 = 4 VGPR
typedef float f32x4  __attribute__((ext_vector_type(4)));
typedef float f32x16 __attribute__((ext_vector_type(16)));
typedef unsigned int u32x4 __attribute__((ext_vector_type(4)));

typedef const __attribute__((address_space(1))) void* gas_cvp;
typedef __attribute__((address_space(3))) void* las_vp;

__device__ __forceinline__ void gload_lds16(const void* g, void* l) {
  __builtin_amdgcn_global_load_lds((gas_cvp)g, (las_vp)l, 16, 0, 0);
}

__device__ __forceinline__ short f2bf(float f) {
  __hip_bfloat16 h = __float2bfloat16(f);
  return *reinterpret_cast<short*>(&h);
}
__device__ __forceinline__ float bf2f(short s) {
  unsigned u = ((unsigned)(unsigned short)s) << 16;
  return __builtin_bit_cast(float, u);
}

#if __has_builtin(__builtin_amdgcn_exp2f)
#define EXP2(x) __builtin_amdgcn_exp2f(x)
#else
#define EXP2(x) exp2f(x)
#endif

constexpr int BATCH = 2;
constexpr int SEQ   = 2048;
constexpr int NH    = 16;
constexpr int MROWS = BATCH * SEQ;   // 4096
constexpr int NSPLIT = 2;            // K-direction split for occupancy
constexpr int KSPL   = SEQ / NSPLIT; // keys per split = 1024
constexpr int RH     = MROWS * NH;   // rowheads = 65536

// ------------------------------- small kernels -----------------------------

__global__ __launch_bounds__(256) void cvt_bf16(const float* __restrict__ src,
                                                short* __restrict__ dst, int n4) {
  int i = blockIdx.x * 256 + threadIdx.x;
  if (i >= n4) return;
  float4 v = reinterpret_cast<const float4*>(src)[i];
  short4 o;
  o.x = f2bf(v.x); o.y = f2bf(v.y); o.z = f2bf(v.z); o.w = f2bf(v.w);
  reinterpret_cast<short4*>(dst)[i] = o;
}

// six 1024x1024 fp32->bf16 transposes in one launch (blockIdx.z selects).
// dst row = n*mul + add  (mul=2 interleaves W1/W2 for the fused-GLU GEMM).
struct WtA {
  const float* s[6];
  short* d[6];
  int st[6];
  int mul[6];
  int add[6];
};
__global__ __launch_bounds__(256) void wtrans6(WtA a) {
  __shared__ float tile[32][33];
  const float* __restrict__ src = a.s[blockIdx.z];
  short* __restrict__ dst = a.d[blockIdx.z];
  const int stride = a.st[blockIdx.z];
  const int mul = a.mul[blockIdx.z], add = a.add[blockIdx.z];
  const int tx = threadIdx.x & 31, ty = threadIdx.x >> 5;   // 32 x 8
  const int n0 = blockIdx.x * 32, k0 = blockIdx.y * 32;
  #pragma unroll
  for (int i = 0; i < 32; i += 8)
    tile[ty + i][tx] = src[(size_t)(k0 + ty + i) * stride + n0 + tx];
  __syncthreads();
  #pragma unroll
  for (int i = 0; i < 32; i += 8)
    dst[(size_t)((n0 + ty + i) * mul + add) * 1024 + k0 + tx] = f2bf(tile[tx][ty + i]);
}

// V-part of QKV [4096][3072] (cols 2048..3071) -> VT [2][1024][2048] bf16
__global__ __launch_bounds__(256) void vtrans(const short* __restrict__ qkv,
                                              short* __restrict__ vt) {
  __shared__ short tile[32][33];
  const int tx = threadIdx.x & 31, ty = threadIdx.x >> 5;
  const int s0 = blockIdx.x * 32, d0 = blockIdx.y * 32, b = blockIdx.z;
  #pragma unroll
  for (int i = 0; i < 32; i += 8)
    tile[ty + i][tx] = qkv[(size_t)(b * SEQ + s0 + ty + i) * 3072 + 2048 + d0 + tx];
  __syncthreads();
  #pragma unroll
  for (int i = 0; i < 32; i += 8)
    vt[(size_t)(b * 1024 + d0 + ty + i) * SEQ + s0 + tx] = tile[tx][ty + i];
}

// ball = [bq | bkv | interleaved {b1,b2}]  (5120 floats)
__global__ void pack_bias(const float* __restrict__ bq, const float* __restrict__ bkv,
                          const float* __restrict__ b1, const float* __restrict__ b2,
                          float* __restrict__ ball) {
  int i = blockIdx.x * 256 + threadIdx.x;
  if (i < 1024) ball[i] = bq[i];
  else if (i < 3072) ball[i] = bkv[i - 1024];
  else if (i < 4096) {
    const int j = i - 3072;
    ball[3072 + 2 * j] = b1[j];
    ball[3072 + 2 * j + 1] = b2[j];
  }
}

__device__ __forceinline__ bool mask_at(const void* mp, int idx, int flag) {
  if (flag == 1) return ((const int*)mp)[idx] != 0;
  if (flag == 2) return ((const float*)mp)[idx] != 0.f;
  return ((const unsigned char*)mp)[idx] != 0;
}

// mask -> additive bias in exp2 domain, with inline dtype detection (mask bool
// may arrive as u8 / i32 / f32). Static-max softmax: fixed -8 shift folded in.
__global__ __launch_bounds__(256) void premask(const void* __restrict__ msk,
                                               float* __restrict__ mbL) {
  __shared__ int si, sf;
  const unsigned* m = (const unsigned*)msk;
  if (threadIdx.x == 0) { si = 1; sf = 1; }
  __syncthreads();
  bool oki = true, okf = true;
  for (int i = threadIdx.x; i < 1024; i += 256) {   // first 4096 bytes, in-bounds always
    unsigned v = m[i];
    oki = oki && (v <= 1u);
    okf = okf && (v == 0u || v == 0x3F800000u);
  }
  if (!oki) si = 0;
  if (!okf) sf = 0;
  __syncthreads();
  const int flag = si ? 1 : (sf ? 2 : 0);
  int i = blockIdx.x * 256 + threadIdx.x;
  if (i < MROWS) mbL[i] = mask_at(msk, i, flag) ? -1.442695e9f : -8.0f;
}

// ------------------------------- GEMM --------------------------------------
// m97 structure, BK=64 (half the barrier drains of BK=32), and conflict-free
// LDS via pre-swizzled source (G21): chunk c of row r stored at position
// c^(r&7); staging dest stays linear-in-tid (global_load_lds requirement),
// the XOR is applied to the per-thread GLOBAL source chunk.  Frag reads are
// per-lane base + compile-time immediates; 2 lanes/bank (free).
//
// Per-lane read base math: lane l (lr=l&15, g=l>>4) reading frag row R+lr,
// kstep s, needs stored chunk (4s+g)^(lr&7) = 4*(s^fl) + (g^(l&3)), fl=(l>>2)&1.

// gemm_bf16<BN>: plain bf16 out, BN = 128 or 64 cols/block.
template <int BN>
__global__ __launch_bounds__(256) void gemm_bf16(const short* __restrict__ A,
                                                 const short* __restrict__ BT,
                                                 const float* __restrict__ bias,
                                                 short* __restrict__ outp, int N) {
  constexpr int NF = BN / 64;     // B-frags per wave per kstep (2 or 1)
  __shared__ short Alds[128 * 64];
  __shared__ short Blds[BN * 64];
  const int tid = threadIdx.x;
  const int w = tid >> 6, l = tid & 63, lr = l & 15;
  const int wr = w >> 1, wc = w & 1;
  const int bm = blockIdx.y, bn = blockIdx.x;

  f32x4 acc[4][2 * NF] = {};

  // staging: thread covers row q*32+(tid>>3), stored-chunk tid&7,
  // source chunk (tid&7)^((tid>>3)&7)
  const int srow = tid >> 3;
  const int schunk = (tid & 7) ^ (srow & 7);
  const short* Ab = A  + (size_t)(bm * 128 + srow) * 1024 + schunk * 8;
  const short* Bb = BT + (size_t)(bn * BN + srow) * 1024 + schunk * 8;

  // per-lane read bases (shorts)
  const int cg = (l >> 4) ^ (l & 3), fl = (l >> 2) & 1;
  const short* ard[2] = { &Alds[(wr * 64 + lr) * 64 + cg * 8 + fl * 32],
                          &Alds[(wr * 64 + lr) * 64 + cg * 8 + 32 - fl * 32] };
  const short* brd[2] = { &Blds[(wc * (BN / 2) + lr) * 64 + cg * 8 + fl * 32],
                          &Blds[(wc * (BN / 2) + lr) * 64 + cg * 8 + 32 - fl * 32] };

  for (int kt = 0; kt < 16; ++kt) {
    const int kb = kt * 64;
    __syncthreads();
    #pragma unroll
    for (int q = 0; q < 4; ++q)
      gload_lds16(Ab + (size_t)q * 32 * 1024 + kb, &Alds[q * 2048 + tid * 8]);
    #pragma unroll
    for (int q = 0; q < BN / 32; ++q)
      gload_lds16(Bb + (size_t)q * 32 * 1024 + kb, &Blds[q * 2048 + tid * 8]);
    asm volatile("s_waitcnt vmcnt(0)" ::: "memory");
    __syncthreads();

    #pragma unroll
    for (int s = 0; s < 2; ++s) {
      bf16x8 af[4], bfr[2 * NF];
      #pragma unroll
      for (int m = 0; m < 4; ++m)
        af[m] = *reinterpret_cast<const bf16x8*>(ard[s] + m * 16 * 64);
      #pragma unroll
      for (int n = 0; n < 2 * NF; ++n)
        bfr[n] = *reinterpret_cast<const bf16x8*>(brd[s] + n * 16 * 64);
      #pragma unroll
      for (int m = 0; m < 4; ++m)
        #pragma unroll
        for (int n = 0; n < 2 * NF; ++n)
          acc[m][n] = __builtin_amdgcn_mfma_f32_16x16x32_bf16(af[m], bfr[n], acc[m][n], 0, 0, 0);
    }
  }

  const int g = l >> 4;
  #pragma unroll
  for (int m = 0; m < 4; ++m) {
    const int row = bm * 128 + wr * 64 + m * 16 + g * 4;
    #pragma unroll
    for (int n = 0; n < 2 * NF; ++n) {
      const int col = bn * BN + wc * (BN / 2) + n * 16 + lr;
      const float bv = bias[col];
      #pragma unroll
      for (int r = 0; r < 4; ++r)
        outp[(size_t)(row + r) * N + col] = f2bf(acc[m][n][r] + bv);
    }
  }
}

// Fused QKV + GLU GEMM: B = [WqkvT (3072 rows) | W12T interleaved (2048 rows)],
// 5120 total, grid (40, 32).  bn<24 -> QKV bf16 out [4096][3072];
// bn>=24 -> GLU: even lanes write sigmoid(x1)*x2 to X1 [4096][1024].
__global__ __launch_bounds__(256) void gemm_qkvglu(const short* __restrict__ A,
                                                   const short* __restrict__ BT,
                                                   const float* __restrict__ bias,
                                                   short* __restrict__ qkv,
                                                   short* __restrict__ x1) {
  __shared__ short Alds[128 * 64];
  __shared__ short Blds[128 * 64];
  const int tid = threadIdx.x;
  const int w = tid >> 6, l = tid & 63, lr = l & 15;
  const int wr = w >> 1, wc = w & 1;
  const int bm = blockIdx.y, bn = blockIdx.x;

  f32x4 acc[4][4] = {};

  const int srow = tid >> 3;
  const int schunk = (tid & 7) ^ (srow & 7);
  const short* Ab = A  + (size_t)(bm * 128 + srow) * 1024 + schunk * 8;
  const short* Bb = BT + (size_t)(bn * 128 + srow) * 1024 + schunk * 8;

  const int cg = (l >> 4) ^ (l & 3), fl = (l >> 2) & 1;
  const short* ard[2] = { &Alds[(wr * 64 + lr) * 64 + cg * 8 + fl * 32],
                          &Alds[(wr * 64 + lr) * 64 + cg * 8 + 32 - fl * 32] };
  const short* brd[2] = { &Blds[(wc * 64 + lr) * 64 + cg * 8 + fl * 32],
                          &Blds[(wc * 64 + lr) * 64 + cg * 8 + 32 - fl * 32] };

  for (int kt = 0; kt < 16; ++kt) {
    const int kb = kt * 64;
    __syncthreads();
    #pragma unroll
    for (int q = 0; q < 4; ++q) {
      gload_lds16(Ab + (size_t)q * 32 * 1024 + kb, &Alds[q * 2048 + tid * 8]);
      gload_lds16(Bb + (size_t)q * 32 * 1024 + kb, &Blds[q * 2048 + tid * 8]);
    }
    asm volatile("s_waitcnt vmcnt(0)" ::: "memory");
    __syncthreads();

    #pragma unroll
    for (int s = 0; s < 2; ++s) {
      bf16x8 af[4], bfr[4];
      #pragma unroll
      for (int m = 0; m < 4; ++m)
        af[m] = *reinterpret_cast<const bf16x8*>(ard[s] + m * 16 * 64);
      #pragma unroll
      for (int n = 0; n < 4; ++n)
        bfr[n] = *reinterpret_cast<const bf16x8*>(brd[s] + n * 16 * 64);
      #pragma unroll
      for (int m = 0; m < 4; ++m)
        #pragma unroll
        for (int n = 0; n < 4; ++n)
          acc[m][n] = __builtin_amdgcn_mfma_f32_16x16x32_bf16(af[m], bfr[n], acc[m][n], 0, 0, 0);
    }
  }

  const int g = l >> 4;
  const bool isGlu = (bn >= 24);
  #pragma unroll
  for (int m = 0; m < 4; ++m) {
    const int row = bm * 128 + wr * 64 + m * 16 + g * 4;
    #pragma unroll
    for (int n = 0; n < 4; ++n) {
      const int col = bn * 128 + wc * 64 + n * 16 + lr;
      const float bv = bias[col];
      #pragma unroll
      for (int r = 0; r < 4; ++r) {
        const float v = acc[m][n][r] + bv;
        if (!isGlu) {
          qkv[(size_t)(row + r) * 3072 + col] = f2bf(v);
        } else {
          // interleaved cols: even lane = x1, odd neighbor = x2
          const float vp = __shfl_xor(v, 1);
          if (!(lr & 1)) {
            const int col2 = col - 3072;
            x1[(size_t)(row + r) * 1024 + (col2 >> 1)] = f2bf(vp / (1.f + __expf(-v)));
          }
        }
      }
    }
  }
}

// ------------------------------- attention v8 -------------------------------
// Swapped-operand 32x32x16, 2-way K-split, KB=64, double-buffer granule-padded
// LDS with reg staging and ONE barrier per tile:
//   loadTile(t+1) -> compute(cur) -> writeTile(cur^1) -> barrier.
// Conflict-free frag reads with compile-time immediate offsets.  Static-max
// softmax, permlane32_swap P redistribution, setprio on MFMA clusters.
constexpr int KB = 64;               // keys per tile
constexpr int KSLOT = 8 * 66;        // K granule-major [8][66] 16B slots
constexpr int VSLOT = 8 * 66;        // V^T granule-major [8][66]

__global__ __launch_bounds__(256) void attn_kernel(const short* __restrict__ qkv,
                                                   const short* __restrict__ vt,
                                                   const float* __restrict__ mbL,
                                                   short* __restrict__ opart,
                                                   float* __restrict__ spart) {
  __shared__ short Kl[2][KSLOT * 8];   // 2 x 8.25 KB
  __shared__ short Vl[2][VSLOT * 8];   // 2 x 8.25 KB
  __shared__ float mb[KSPL];           // 4 KB mask bias (log2 domain, -8 shift)

  const int tid = threadIdx.x;
  const int w = tid >> 6, lane = tid & 63, ql = lane & 31, hi = lane >> 5;
  const int sp = blockIdx.x & (NSPLIT - 1), qb = blockIdx.x / NSPLIT;
  const int h = blockIdx.y, b = blockIdx.z;
  const int qrow = qb * 128 + w * 32 + ql;
  const int kofs = sp * KSPL;

  // ---- hoist Q fragments (B-operand: lane q holds Q[q][c*16 + hi*8 + j]) ----
  bf16x8 qf[4];
  {
    const short* qp = qkv + (size_t)(b * SEQ + qrow) * 3072 + h * 64;
    #pragma unroll
    for (int c = 0; c < 4; ++c)
      qf[c] = *reinterpret_cast<const bf16x8*>(qp + c * 16 + hi * 8);
  }

  // ---- staging maps (per-thread constants) ----
  const short* gkbase = qkv + (size_t)(b * SEQ + kofs) * 3072 + 1024 + h * 64
                        + (size_t)(tid >> 3) * 3072 + (tid & 7) * 8;
  const short* gvbase = vt + ((size_t)(b * 1024 + h * 64) + (tid >> 3)) * SEQ + kofs
                        + (tid & 7) * 8;
  short* kwr = &Kl[0][((tid & 7) * 66 + (tid >> 3)) * 8];
  short* vwr = &Vl[0][((tid & 7) * 66 + (tid >> 3)) * 8];

  u32x4 kreg0, kreg1, vreg0, vreg1;
  auto loadTile = [&](int kt) {
    const short* gk = gkbase + (size_t)kt * KB * 3072;
    kreg0 = *reinterpret_cast<const u32x4*>(gk);
    kreg1 = *reinterpret_cast<const u32x4*>(gk + 32 * 3072);
    const short* gv = gvbase + kt * KB;
    vreg0 = *reinterpret_cast<const u32x4*>(gv);
    vreg1 = *reinterpret_cast<const u32x4*>(gv + 32 * SEQ);
  };
  auto writeTile = [&](int buf) {
    short* kd = kwr + buf * KSLOT * 8;
    *reinterpret_cast<u32x4*>(kd)          = kreg0;   // compiler waits vmcnt here
    *reinterpret_cast<u32x4*>(kd + 32 * 8) = kreg1;
    short* vd = vwr + buf * VSLOT * 8;
    *reinterpret_cast<u32x4*>(vd)          = vreg0;
    *reinterpret_cast<u32x4*>(vd + 32 * 8) = vreg1;
  };

  float s_run = 0.f;
  f32x16 oacc0 = {}, oacc1 = {};

  // ---- prologue: mask bias (4KB, all waves) + tile 0 ----
  gload_lds16(mbL + b * SEQ + kofs + tid * 4, &mb[tid * 4]);
  loadTile(0);
  writeTile(0);
  __syncthreads();

  // per-lane LDS read bases (constant; reads use +imm offsets)
  const short* krd = &Kl[0][(hi * 66 + ql) * 8];
  const short* vrd = &Vl[0][(hi * 66 + ql) * 8];

  constexpr int NT = KSPL / KB;   // 16
  for (int kt = 0; kt < NT; ++kt) {
    const int cur = kt & 1;
    if (kt + 1 < NT) loadTile(kt + 1);   // HBM latency hides under compute(t)
    const short* Kb = krd + cur * KSLOT * 8;
    const short* Vb = vrd + cur * VSLOT * 8;

    #pragma unroll
    for (int t2 = 0; t2 < 2; ++t2) {
      // QK^T: S[k][q]
      f32x16 sc = {};
      __builtin_amdgcn_s_setprio(1);
      #pragma unroll
      for (int c = 0; c < 4; ++c) {
        bf16x8 kf = *reinterpret_cast<const bf16x8*>(Kb + (c * 132 + t2 * 32) * 8);
        sc = __builtin_amdgcn_mfma_f32_32x32x16_bf16(kf, qf[c], sc, 0, 0, 0);
      }
      __builtin_amdgcn_s_setprio(0);
      // p = exp2(score*scale*log2e + bias)   (bias = mask? -1.4e9 : -8)
      float p[16];
      #pragma unroll
      for (int u = 0; u < 4; ++u) {
        float4 m4 = *reinterpret_cast<const float4*>(&mb[kt * KB + t2 * 32 + u * 8 + hi * 4]);
        p[4 * u + 0] = EXP2(fmaf(sc[4 * u + 0], 0.18033688f, m4.x));   // 0.125*log2e
        p[4 * u + 1] = EXP2(fmaf(sc[4 * u + 1], 0.18033688f, m4.y));
        p[4 * u + 2] = EXP2(fmaf(sc[4 * u + 2], 0.18033688f, m4.z));
        p[4 * u + 3] = EXP2(fmaf(sc[4 * u + 3], 0.18033688f, m4.w));
      }
      // partial-sum tree (cross-lane deferred to epilogue)
      {
        float a0 = (p[0] + p[1]) + (p[2] + p[3]);
        float a1 = (p[4] + p[5]) + (p[6] + p[7]);
        float a2 = (p[8] + p[9]) + (p[10] + p[11]);
        float a3 = (p[12] + p[13]) + (p[14] + p[15]);
        s_run += (a0 + a1) + (a2 + a3);
      }
      // pack P -> bf16 pairs; permlane32_swap redistributes across half-waves
      unsigned P[8];
      #pragma unroll
      for (int j = 0; j < 8; ++j)
        asm("v_cvt_pk_bf16_f32 %0, %1, %2" : "=v"(P[j]) : "v"(p[2 * j]), "v"(p[2 * j + 1]));
      asm("v_permlane32_swap_b32 %0, %1" : "+v"(P[0]), "+v"(P[2]));
      asm("v_permlane32_swap_b32 %0, %1" : "+v"(P[1]), "+v"(P[3]));
      asm("v_permlane32_swap_b32 %0, %1" : "+v"(P[4]), "+v"(P[6]));
      asm("v_permlane32_swap_b32 %0, %1" : "+v"(P[5]), "+v"(P[7]));
      u32x4 c0 = { P[0], P[1], P[2], P[3] };
      u32x4 c1 = { P[4], P[5], P[6], P[7] };
      bf16x8 pf[2] = { __builtin_bit_cast(bf16x8, c0), __builtin_bit_cast(bf16x8, c1) };

      // PV: O^T[d][q] += V^T[d][k] P[k][q]
      __builtin_amdgcn_s_setprio(1);
      #pragma unroll
      for (int ch = 0; ch < 2; ++ch) {
        const int gb = (t2 * 4 + ch * 2) * 66;
        bf16x8 v0 = *reinterpret_cast<const bf16x8*>(Vb + gb * 8);
        bf16x8 v1 = *reinterpret_cast<const bf16x8*>(Vb + (gb + 32) * 8);
        oacc0 = __builtin_amdgcn_mfma_f32_32x32x16_bf16(v0, pf[ch], oacc0, 0, 0, 0);
        oacc1 = __builtin_amdgcn_mfma_f32_32x32x16_bf16(v1, pf[ch], oacc1, 0, 0, 0);
      }
      __builtin_amdgcn_s_setprio(0);
    }

    if (kt + 1 < NT) {
      writeTile(cur ^ 1);   // cur^1 readers finished at end of tile kt-1
      __syncthreads();      // writes visible before tile kt+1 reads
    }
  }

  // ---- epilogue: finish sum across half-waves, store unnormalized O + s ----
  const float sT = s_run + __shfl_xor(s_run, 32);
  const size_t obase = (size_t)sp * RH * 64 + (size_t)(b * SEQ + qrow) * 1024 + h * 64;
  #pragma unroll
  for (int dt = 0; dt < 2; ++dt) {
    #pragma unroll
    for (int u = 0; u < 4; ++u) {
      short4 st;
      const f32x16& oa = dt ? oacc1 : oacc0;
      st.x = f2bf(oa[4 * u + 0]);
      st.y = f2bf(oa[4 * u + 1]);
      st.z = f2bf(oa[4 * u + 2]);
      st.w = f2bf(oa[4 * u + 3]);
      *reinterpret_cast<short4*>(&opart[obase + dt * 32 + u * 8 + hi * 4]) = st;
    }
  }
  if (hi == 0)
    spart[sp * RH + (b * SEQ + qrow) * NH + h] = sT;
}

// merge K-splits: att = sum(O_s) / sum(s_s)   (same fixed shift cancels)
__global__ __launch_bounds__(256) void attn_merge(const short* __restrict__ opart,
                                                  const float* __restrict__ spart,
                                                  short* __restrict__ att) {
  const int idx = blockIdx.x * 256 + threadIdx.x;   // RH*8 = 524288
  const int rh = idx >> 3;
  const size_t base = (size_t)rh * 64 + (idx & 7) * 8;
  float acc[8] = {};
  float ss = 0.f;
  #pragma unroll
  for (int s = 0; s < NSPLIT; ++s) {
    bf16x8 o = *reinterpret_cast<const bf16x8*>(&opart[(size_t)s * RH * 64 + base]);
    #pragma unroll
    for (int j = 0; j < 8; ++j) acc[j] += bf2f(o[j]);
    ss += spart[s * RH + rh];
  }
  const float inv = 1.f / ss;
  bf16x8 r;
  #pragma unroll
  for (int j = 0; j < 8; ++j) r[j] = f2bf(acc[j] * inv);
  *reinterpret_cast<bf16x8*>(&att[base]) = r;
}

// -------------------------- residual + LayerNorm ----------------------------
__global__ __launch_bounds__(256) void ln_kernel(const float* __restrict__ h,
                                                 const short* __restrict__ ao,
                                                 const short* __restrict__ gl,
                                                 const float* __restrict__ gamma,
                                                 const float* __restrict__ beta,
                                                 float* __restrict__ out) {
  const int row = blockIdx.x;
  const size_t base = (size_t)row * 1024;
  const int t = threadIdx.x;
  __shared__ float red[4];
  float x[4];
  #pragma unroll
  for (int j = 0; j < 4; ++j) {
    const int c = t + j * 256;
    x[j] = h[base + c] + bf2f(ao[base + c]) + bf2f(gl[base + c]);
  }
  float s = x[0] + x[1] + x[2] + x[3];
  #pragma unroll
  for (int d = 1; d < 64; d <<= 1) s += __shfl_xor(s, d);
  if ((t & 63) == 0) red[t >> 6] = s;
  __syncthreads();
  const float mu = (red[0] + red[1] + red[2] + red[3]) * (1.f / 1024.f);
  __syncthreads();
  float vs = 0.f;
  #pragma unroll
  for (int j = 0; j < 4; ++j) { const float dx = x[j] - mu; vs += dx * dx; }
  #pragma unroll
  for (int d = 1; d < 64; d <<= 1) vs += __shfl_xor(vs, d);
  if ((t & 63) == 0) red[t >> 6] = vs;
  __syncthreads();
  const float var = (red[0] + red[1] + red[2] + red[3]) * (1.f / 1024.f);
  const float rs = rsqrtf(var + 1e-6f);
  #pragma unroll
  for (int j = 0; j < 4; ++j) {
    const int c = t + j * 256;
    out[base + c] = (x[j] - mu) * rs * gamma[c] + beta[c];
  }
}

// ------------------------------- launcher ----------------------------------

extern "C" void kernel_launch(void* const* d_in, const int* in_sizes, int n_in,
                              void* d_out, int out_size, void* d_ws, size_t ws_size,
                              hipStream_t stream) {
  const float* h   = (const float*)d_in[0];
  const void*  msk = d_in[1];
  const float* Wq  = (const float*)d_in[2];
  const float* bq  = (const float*)d_in[3];
  const float* Wkv = (const float*)d_in[4];
  const float* bkv = (const float*)d_in[5];
  const float* Wo  = (const float*)d_in[6];
  const float* bo  = (const float*)d_in[7];
  const float* W1  = (const float*)d_in[8];
  const float* b1  = (const float*)d_in[9];
  const float* W2  = (const float*)d_in[10];
  const float* b2  = (const float*)d_in[11];
  const float* lng = (const float*)d_in[12];
  const float* lnb = (const float*)d_in[13];
  float* out = (float*)d_out;

  char* ws = (char*)d_ws;
  size_t off = 0;
  auto alloc = [&](size_t bytes) {
    char* p = ws + off;
    off += (bytes + 255) & ~(size_t)255;
    return p;
  };
  short* X     = (short*)alloc((size_t)MROWS * 1024 * 2);   // h in bf16
  short* WALL  = (short*)alloc((size_t)5120 * 1024 * 2);    // [Wq|Wkv|W1/W2 ilv]^T
  short* WoT   = (short*)alloc((size_t)1024 * 1024 * 2);
  float* ball  = (float*)alloc(5120 * 4);
  float* MBL   = (float*)alloc((size_t)MROWS * 4);          // mask bias (log2 dom)
  short* QKV   = (short*)alloc((size_t)MROWS * 3072 * 2);
  short* VT    = (short*)alloc((size_t)BATCH * 1024 * SEQ * 2);  // V transposed
  short* ATT   = (short*)alloc((size_t)MROWS * 1024 * 2);
  short* X1    = (short*)alloc((size_t)MROWS * 1024 * 2);   // GLU result bf16
  short* AO    = (short*)alloc((size_t)MROWS * 1024 * 2);   // attention proj bf16
  short* OP    = (short*)alloc((size_t)NSPLIT * RH * 64 * 2);  // partial O (unnorm)
  float* SP    = (float*)alloc((size_t)NSPLIT * RH * 4);       // partial sums
  if (off > ws_size) return;  // workspace too small: bail visibly

  cvt_bf16<<<4096, 256, 0, stream>>>(h, X, MROWS * 1024 / 4);
  WtA wa;
  wa.s[0] = Wq;          wa.d[0] = WALL;                wa.st[0] = 1024;  wa.mul[0] = 1; wa.add[0] = 0;
  wa.s[1] = Wkv;         wa.d[1] = WALL + 1024 * 1024;  wa.st[1] = 2048;  wa.mul[1] = 1; wa.add[1] = 0;
  wa.s[2] = Wkv + 1024;  wa.d[2] = WALL + 2048 * 1024;  wa.st[2] = 2048;  wa.mul[2] = 1; wa.add[2] = 0;
  wa.s[3] = Wo;          wa.d[3] = WoT;                 wa.st[3] = 1024;  wa.mul[3] = 1; wa.add[3] = 0;
  wa.s[4] = W1;          wa.d[4] = WALL + 3072 * 1024;  wa.st[4] = 1024;  wa.mul[4] = 2; wa.add[4] = 0;
  wa.s[5] = W2;          wa.d[5] = WALL + 3072 * 1024;  wa.st[5] = 1024;  wa.mul[5] = 2; wa.add[5] = 1;
  wtrans6<<<dim3(32, 32, 6), 256, 0, stream>>>(wa);
  pack_bias<<<16, 256, 0, stream>>>(bq, bkv, b1, b2, ball);
  premask<<<16, 256, 0, stream>>>(msk, MBL);

  // fused QKV + GLU projection (one 1280-block dispatch)
  gemm_qkvglu<<<dim3(40, 32), 256, 0, stream>>>(X, WALL, ball, QKV, X1);
  // V transpose for attention A-operand
  vtrans<<<dim3(64, 32, 2), 256, 0, stream>>>(QKV, VT);
  // flash attention, 2-way K-split -> partials, then merge -> ATT
  attn_kernel<<<dim3(16 * NSPLIT, 16, 2), 256, 0, stream>>>(QKV, VT, MBL, OP, SP);
  attn_merge<<<RH * 8 / 256, 256, 0, stream>>>(OP, SP, ATT);
  // attention out projection: BN=64 tile -> 512 blocks (2/CU)
  gemm_bf16<64><<<dim3(16, 32), 256, 0, stream>>>(ATT, WoT, bo, AO, 1024);
  // out = LayerNorm(h + AO + X1)
  ln_kernel<<<MROWS, 256, 0, stream>>>(h, AO, X1, lng, lnb, out);
}